// Round 16
// baseline (596.330 us; speedup 1.0000x reference)
//
#include <hip/hip_runtime.h>

#define B_ 128
#define T_ 512
#define D_ 512
#define H_ 64
#define N3 192   // 3*H
#define MB 16    // batch rows per scan block

#if __has_builtin(__builtin_amdgcn_rcpf)
#define RCP(x) __builtin_amdgcn_rcpf(x)
#else
#define RCP(x) (1.0f / (x))
#endif

typedef _Float16 f16x8 __attribute__((ext_vector_type(8)));
typedef float f32x4 __attribute__((ext_vector_type(4)));

__device__ __forceinline__ float sigm_f(float x) {
  return RCP(1.0f + __expf(-x));
}
__device__ __forceinline__ float tanh_f(float x) {
  float e = __expf(-2.0f * fabsf(x));
  float t = (1.0f - e) * RCP(1.0f + e);
  return copysignf(t, x);
}

#define KEEP(x) asm volatile("" : "+v"(x))
#define KEEPV(v) do { int4& kr_ = *reinterpret_cast<int4*>(&(v)); \
  KEEP(kr_.x); KEEP(kr_.y); KEEP(kr_.z); KEEP(kr_.w); } while (0)

// ---------------- pass 1 (r15, verified): gi0 = X @ W0ih^T + b0ih + act flags ----------------
__global__ __launch_bounds__(256) void gemm_kernel(
    const float* __restrict__ x,     // [B,T,D]
    const float* __restrict__ w0ih,  // [N3,D]
    const float* __restrict__ b0ih,  // [N3]
    float* __restrict__ gi0,         // [B,Tc,N3]
    int* __restrict__ act,           // [T]
    int t0, int Tc) {
  __shared__ _Float16 Xs[64][72];
  __shared__ _Float16 Ws[64][72];
  __shared__ unsigned char sflag[64];

  const int tid = threadIdx.x;
  const int bid = blockIdx.x;
  const int nt = bid % 3;
  const int mt = bid / 3;
  const int tpc = Tc >> 6;
  const int b  = mt / tpc;
  const int tt = mt % tpc;
  const int c0 = nt * 64;

  const int lane = tid & 63;
  const int wid  = tid >> 6;
  const int wm = (wid >> 1) * 32;
  const int wn = (wid & 1) * 32;
  const int l15 = lane & 15;
  const int l4  = lane >> 4;

  const float* xbase = x + ((size_t)b * T_ + t0 + tt * 64) * D_;
  const float* wbase = w0ih + (size_t)c0 * D_;

  const int srow = tid >> 2;
  const int scg  = (tid & 3) << 4;
  const float* xrow = xbase + (size_t)srow * D_;
  const float* wrow = wbase + (size_t)srow * D_;

  f32x4 acc[2][2];
#pragma unroll
  for (int mi = 0; mi < 2; ++mi)
#pragma unroll
    for (int ni = 0; ni < 2; ++ni) {
      acc[mi][ni].x = 0.f; acc[mi][ni].y = 0.f;
      acc[mi][ni].z = 0.f; acc[mi][ni].w = 0.f;
    }

  bool f = false;

  for (int kt = 0; kt < D_ / 64; ++kt) {
    const int k0 = kt * 64 + scg;
    float4 xa = *(const float4*)&xrow[k0];
    float4 xb = *(const float4*)&xrow[k0 + 4];
    float4 xc = *(const float4*)&xrow[k0 + 8];
    float4 xd = *(const float4*)&xrow[k0 + 12];
    float4 wa = *(const float4*)&wrow[k0];
    float4 wb = *(const float4*)&wrow[k0 + 4];
    float4 wc = *(const float4*)&wrow[k0 + 8];
    float4 wd = *(const float4*)&wrow[k0 + 12];
    f |= (xa.x != 0.f) | (xa.y != 0.f) | (xa.z != 0.f) | (xa.w != 0.f) |
         (xb.x != 0.f) | (xb.y != 0.f) | (xb.z != 0.f) | (xb.w != 0.f) |
         (xc.x != 0.f) | (xc.y != 0.f) | (xc.z != 0.f) | (xc.w != 0.f) |
         (xd.x != 0.f) | (xd.y != 0.f) | (xd.z != 0.f) | (xd.w != 0.f);
    __syncthreads();
    {
      f16x8 p0 = {(_Float16)xa.x, (_Float16)xa.y, (_Float16)xa.z, (_Float16)xa.w,
                  (_Float16)xb.x, (_Float16)xb.y, (_Float16)xb.z, (_Float16)xb.w};
      f16x8 p1 = {(_Float16)xc.x, (_Float16)xc.y, (_Float16)xc.z, (_Float16)xc.w,
                  (_Float16)xd.x, (_Float16)xd.y, (_Float16)xd.z, (_Float16)xd.w};
      *(f16x8*)&Xs[srow][scg] = p0;
      *(f16x8*)&Xs[srow][scg + 8] = p1;
      f16x8 q0 = {(_Float16)wa.x, (_Float16)wa.y, (_Float16)wa.z, (_Float16)wa.w,
                  (_Float16)wb.x, (_Float16)wb.y, (_Float16)wb.z, (_Float16)wb.w};
      f16x8 q1 = {(_Float16)wc.x, (_Float16)wc.y, (_Float16)wc.z, (_Float16)wc.w,
                  (_Float16)wd.x, (_Float16)wd.y, (_Float16)wd.z, (_Float16)wd.w};
      *(f16x8*)&Ws[srow][scg] = q0;
      *(f16x8*)&Ws[srow][scg + 8] = q1;
    }
    __syncthreads();
#pragma unroll
    for (int ks = 0; ks < 2; ++ks) {
      const int kb = ks * 32 + l4 * 8;
      f16x8 a0 = *(const f16x8*)&Xs[wm + l15][kb];
      f16x8 a1 = *(const f16x8*)&Xs[wm + 16 + l15][kb];
      f16x8 b0 = *(const f16x8*)&Ws[wn + l15][kb];
      f16x8 b1 = *(const f16x8*)&Ws[wn + 16 + l15][kb];
      acc[0][0] = __builtin_amdgcn_mfma_f32_16x16x32_f16(a0, b0, acc[0][0], 0, 0, 0);
      acc[0][1] = __builtin_amdgcn_mfma_f32_16x16x32_f16(a0, b1, acc[0][1], 0, 0, 0);
      acc[1][0] = __builtin_amdgcn_mfma_f32_16x16x32_f16(a1, b0, acc[1][0], 0, 0, 0);
      acc[1][1] = __builtin_amdgcn_mfma_f32_16x16x32_f16(a1, b1, acc[1][1], 0, 0, 0);
    }
  }

  const float bias0 = b0ih[c0 + wn + l15];
  const float bias1 = b0ih[c0 + wn + 16 + l15];
  const size_t rowbase = (size_t)b * Tc + tt * 64;
#pragma unroll
  for (int mi = 0; mi < 2; ++mi)
#pragma unroll
    for (int r = 0; r < 4; ++r) {
      const int m = wm + mi * 16 + l4 * 4 + r;
      float* orow = &gi0[(rowbase + m) * N3 + c0 + wn];
      orow[l15]      = acc[mi][0][r] + bias0;
      orow[16 + l15] = acc[mi][1][r] + bias1;
    }

  if (tid < 64) sflag[tid] = 0;
  __syncthreads();
  if (f) sflag[srow] = 1;
  __syncthreads();
  if (tid < 64 && sflag[tid]) act[t0 + tt * 64 + tid] = 1;
}

// A-fragment read from swizzled h-tile [MB][64] f16: row = l&15, chunk c.
__device__ __forceinline__ f16x8 loadA(const _Float16* hb, int row, int c) {
  int pc = c ^ (row & 7);
  return *(const f16x8*)&hb[row * 64 + 8 * pc];
}
#define MFMA16(A, Bv, C) __builtin_amdgcn_mfma_f32_16x16x32_f16(A, Bv, C, 0, 0, 0)

// ------------- pass 2: MFMA layer-pipelined scan, 8 blocks x 16 batch rows -------------
// 12 waves = 3 layer-groups (r14's verified parity/pipeline schedule, 1
// barrier/tick) x 4 col-waves. Wave (grp,w): C-tiles = rows 16 batch x cols
// {16w, 64+16w, 128+16w} (R/Z/N land in the same lane -> lane-local gates).
// Weights live as per-wave B-FRAGMENTS in registers (48 dwords; cap 170 via
// launch_bounds(768,3)) -> zero weight LDS traffic (was 123KB/tick, the r14
// wall). h tiles in LDS, chunk-XOR swizzle (r15-verified conflict-free).
// Fragment convention identical to r15's PASSING gemm: A row=l&15 k-oct=l>>4;
// B from W row-major [n][k]; C col=l&15, row=(l>>4)*4+reg.
__global__ __launch_bounds__(768, 3) void scan_kernel(
    const float* __restrict__ gi0,   // [B,Tc,N3]
    const float* __restrict__ w0hh, const float* __restrict__ w1ih,
    const float* __restrict__ w1hh, const float* __restrict__ w2ih,
    const float* __restrict__ w2hh,
    const float* __restrict__ b0hh, const float* __restrict__ b1ih,
    const float* __restrict__ b1hh, const float* __restrict__ b2ih,
    const float* __restrict__ b2hh,
    const int* __restrict__ act,     // [T]
    float* __restrict__ hstate,      // [3,B,H]
    float* __restrict__ out,         // [B,T,H]
    int t0, int Tc) {
  const int b0 = blockIdx.x * MB;
  const int tid = threadIdx.x;
  const int lane = tid & 63;
  const int wave = tid >> 6;        // 0..11
  const int grp = wave >> 2;        // layer 0..2
  const int w   = wave & 3;         // col-group
  const int l15 = lane & 15;
  const int l4  = lane >> 4;        // 0..3
  const int j   = 16 * w + l15;     // unit/col id [0,64)

  __shared__ __align__(16) _Float16 s_h[3][2][MB][64];  // 12KB, chunk-swizzled
  __shared__ int s_act[T_];

  for (int i = tid; i < Tc; i += 768) s_act[i] = act[t0 + i];

  // ---- B-fragments (weights) -> registers, f32->f16 ----
  const float* matIH = (grp == 1) ? w1ih : (grp == 2) ? w2ih : w0hh;  // grp0 dummy
  const float* matHH = (grp == 0) ? w0hh : (grp == 1) ? w1hh : w2hh;
  f16x8 bf[2][3][2];   // [0=ih,1=hh][gate][kstep]
#pragma unroll
  for (int m2 = 0; m2 < 2; ++m2) {
    const float* mp = m2 ? matHH : matIH;
#pragma unroll
    for (int g = 0; g < 3; ++g)
#pragma unroll
      for (int ks = 0; ks < 2; ++ks) {
        const float* src = mp + (size_t)(64 * g + j) * H_ + l4 * 8 + 32 * ks;
        f16x8 v;
#pragma unroll
        for (int q = 0; q < 8; ++q) v[q] = (_Float16)src[q];
        bf[m2][g][ks] = v;
      }
  }
#pragma unroll
  for (int m2 = 0; m2 < 2; ++m2)
#pragma unroll
    for (int g = 0; g < 3; ++g)
#pragma unroll
      for (int ks = 0; ks < 2; ++ks) KEEPV(bf[m2][g][ks]);

  // ---- biases (per lane col j) ----
  float bR, bZ, biN, bhN;
  if (grp == 0) {
    bR = b0hh[j]; bZ = b0hh[j + 64]; biN = 0.f; bhN = b0hh[j + 128];
  } else if (grp == 1) {
    bR = b1ih[j] + b1hh[j]; bZ = b1ih[j + 64] + b1hh[j + 64];
    biN = b1ih[j + 128]; bhN = b1hh[j + 128];
  } else {
    bR = b2ih[j] + b2hh[j]; bZ = b2ih[j + 64] + b2hh[j + 64];
    biN = b2ih[j + 128]; bhN = b2hh[j + 128];
  }

  // ---- state: lane owns (rows l4*4+r, col j) of its layer ----
  float hreg[4];
#pragma unroll
  for (int r = 0; r < 4; ++r) {
    int m = l4 * 4 + r;
    float v = (t0 == 0) ? 0.f
                        : hstate[grp * B_ * H_ + (size_t)(b0 + m) * H_ + j];
    hreg[r] = v;
    int pc = (j >> 3) ^ (m & 7);
    s_h[grp][0][m][8 * pc + (j & 7)] = (_Float16)v;
    s_h[grp][1][m][8 * pc + (j & 7)] = (_Float16)v;
  }

  // ---- grp0: gi registers (prefetched per tick) ----
  float giv[3][4];
  if (grp == 0) {
#pragma unroll
    for (int g = 0; g < 3; ++g)
#pragma unroll
      for (int r = 0; r < 4; ++r)
        giv[g][r] = gi0[((size_t)(b0 + l4 * 4 + r) * Tc) * N3 + 64 * g + j];
  }

  __syncthreads();

  const f32x4 zz = {0.f, 0.f, 0.f, 0.f};

  for (int i = 0; i < Tc + 2; ++i) {
    const int p = i & 1;
    if (grp == 0) {
      if (i < Tc) {
        const _Float16* hb = &s_h[0][p ^ 1][0][0];
        f16x8 a0 = loadA(hb, l15, l4);
        f16x8 a1 = loadA(hb, l15, l4 + 4);
        f32x4 aR = MFMA16(a0, bf[1][0][0], zz);
        aR = MFMA16(a1, bf[1][0][1], aR);
        f32x4 aZ = MFMA16(a0, bf[1][1][0], zz);
        aZ = MFMA16(a1, bf[1][1][1], aZ);
        f32x4 aN = MFMA16(a0, bf[1][2][0], zz);
        aN = MFMA16(a1, bf[1][2][1], aN);
        bool a = (s_act[i] != 0);
#pragma unroll
        for (int r = 0; r < 4; ++r) {
          int m = l4 * 4 + r;
          float R = sigm_f(giv[0][r] + aR[r] + bR);
          float Z = sigm_f(giv[1][r] + aZ[r] + bZ);
          float N = tanh_f(giv[2][r] + R * (aN[r] + bhN));
          float hn = (1.f - Z) * N + Z * hreg[r];
          hreg[r] = a ? hn : hreg[r];
          int pc = (j >> 3) ^ (m & 7);
          s_h[0][p][m][8 * pc + (j & 7)] = (_Float16)hreg[r];
        }
        int tn = (i + 1 < Tc) ? i + 1 : Tc - 1;
#pragma unroll
        for (int g = 0; g < 3; ++g)
#pragma unroll
          for (int r = 0; r < 4; ++r)
            giv[g][r] = gi0[((size_t)(b0 + l4 * 4 + r) * Tc + tn) * N3 + 64 * g + j];
      }
    } else if (grp == 1) {
      if (i >= 1 && i <= Tc) {
        const _Float16* hp = &s_h[0][p ^ 1][0][0];
        const _Float16* hs = &s_h[1][p ^ 1][0][0];
        f16x8 p0 = loadA(hp, l15, l4), p1 = loadA(hp, l15, l4 + 4);
        f16x8 s0 = loadA(hs, l15, l4), s1 = loadA(hs, l15, l4 + 4);
        f32x4 aR = MFMA16(p0, bf[0][0][0], zz);
        aR = MFMA16(p1, bf[0][0][1], aR);
        aR = MFMA16(s0, bf[1][0][0], aR);
        aR = MFMA16(s1, bf[1][0][1], aR);
        f32x4 aZ = MFMA16(p0, bf[0][1][0], zz);
        aZ = MFMA16(p1, bf[0][1][1], aZ);
        aZ = MFMA16(s0, bf[1][1][0], aZ);
        aZ = MFMA16(s1, bf[1][1][1], aZ);
        f32x4 aiN = MFMA16(p0, bf[0][2][0], zz);
        aiN = MFMA16(p1, bf[0][2][1], aiN);
        f32x4 ahN = MFMA16(s0, bf[1][2][0], zz);
        ahN = MFMA16(s1, bf[1][2][1], ahN);
        bool a = (s_act[i - 1] != 0);
#pragma unroll
        for (int r = 0; r < 4; ++r) {
          int m = l4 * 4 + r;
          float R = sigm_f(aR[r] + bR);
          float Z = sigm_f(aZ[r] + bZ);
          float N = tanh_f(aiN[r] + biN + R * (ahN[r] + bhN));
          float hn = (1.f - Z) * N + Z * hreg[r];
          hreg[r] = a ? hn : hreg[r];
          int pc = (j >> 3) ^ (m & 7);
          s_h[1][p][m][8 * pc + (j & 7)] = (_Float16)hreg[r];
        }
      }
    } else {
      if (i >= 2) {
        const _Float16* hp = &s_h[1][p ^ 1][0][0];
        const _Float16* hs = &s_h[2][p ^ 1][0][0];
        f16x8 p0 = loadA(hp, l15, l4), p1 = loadA(hp, l15, l4 + 4);
        f16x8 s0 = loadA(hs, l15, l4), s1 = loadA(hs, l15, l4 + 4);
        f32x4 aR = MFMA16(p0, bf[0][0][0], zz);
        aR = MFMA16(p1, bf[0][0][1], aR);
        aR = MFMA16(s0, bf[1][0][0], aR);
        aR = MFMA16(s1, bf[1][0][1], aR);
        f32x4 aZ = MFMA16(p0, bf[0][1][0], zz);
        aZ = MFMA16(p1, bf[0][1][1], aZ);
        aZ = MFMA16(s0, bf[1][1][0], aZ);
        aZ = MFMA16(s1, bf[1][1][1], aZ);
        f32x4 aiN = MFMA16(p0, bf[0][2][0], zz);
        aiN = MFMA16(p1, bf[0][2][1], aiN);
        f32x4 ahN = MFMA16(s0, bf[1][2][0], zz);
        ahN = MFMA16(s1, bf[1][2][1], ahN);
        bool a = (s_act[i - 2] != 0);
        int tcur = t0 + i - 2;
#pragma unroll
        for (int r = 0; r < 4; ++r) {
          int m = l4 * 4 + r;
          float R = sigm_f(aR[r] + bR);
          float Z = sigm_f(aZ[r] + bZ);
          float N = tanh_f(aiN[r] + biN + R * (ahN[r] + bhN));
          float hn = (1.f - Z) * N + Z * hreg[r];
          hreg[r] = a ? hn : hreg[r];
          int pc = (j >> 3) ^ (m & 7);
          s_h[2][p][m][8 * pc + (j & 7)] = (_Float16)hreg[r];
          out[((size_t)(b0 + m) * T_ + tcur) * H_ + j] = a ? hreg[r] : 0.f;
        }
      }
    }
    __syncthreads();   // the ONE barrier per pipeline tick (r14 schedule)
  }

#pragma unroll
  for (int r = 0; r < 4; ++r)
    hstate[grp * B_ * H_ + (size_t)(b0 + l4 * 4 + r) * H_ + j] = hreg[r];
}

extern "C" void kernel_launch(void* const* d_in, const int* in_sizes, int n_in,
                              void* d_out, int out_size, void* d_ws, size_t ws_size,
                              hipStream_t stream) {
  const float* x    = (const float*)d_in[0];
  const float* w0ih = (const float*)d_in[1];
  const float* w0hh = (const float*)d_in[2];
  const float* b0ih = (const float*)d_in[3];
  const float* b0hh = (const float*)d_in[4];
  const float* w1ih = (const float*)d_in[5];
  const float* w1hh = (const float*)d_in[6];
  const float* b1ih = (const float*)d_in[7];
  const float* b1hh = (const float*)d_in[8];
  const float* w2ih = (const float*)d_in[9];
  const float* w2hh = (const float*)d_in[10];
  const float* b2ih = (const float*)d_in[11];
  const float* b2hh = (const float*)d_in[12];
  float* out = (float*)d_out;

  char* p = (char*)d_ws;
  int* act      = (int*)p;    p += 4096;
  float* hstate = (float*)p;  p += (size_t)3 * B_ * H_ * 4;
  size_t fixed = (size_t)(p - (char*)d_ws);

  int Tc = T_;
  while (Tc > 64 && fixed + (size_t)B_ * Tc * N3 * 4 > ws_size) Tc >>= 1;
  float* gi0 = (float*)p;

  hipMemsetAsync(act, 0, T_ * sizeof(int), stream);
  for (int t0 = 0; t0 < T_; t0 += Tc) {
    gemm_kernel<<<dim3(B_ * (Tc / 64) * 3), 256, 0, stream>>>(
        x, w0ih, b0ih, gi0, act, t0, Tc);
    scan_kernel<<<B_ / MB, 768, 0, stream>>>(
        gi0, w0hh, w1ih, w1hh, w2ih, w2hh,
        b0hh, b1ih, b1hh, b2ih, b2hh, act, hstate, out, t0, Tc);
  }
}

// Round 17
// 587.226 us; speedup vs baseline: 1.0155x; 1.0155x over previous
//
#include <hip/hip_runtime.h>

#define B_ 128
#define T_ 512
#define D_ 512
#define H_ 64
#define N3 192   // 3*H
#define MB 16    // batch rows per scan block

#if __has_builtin(__builtin_amdgcn_rcpf)
#define RCP(x) __builtin_amdgcn_rcpf(x)
#else
#define RCP(x) (1.0f / (x))
#endif

typedef _Float16 f16x8 __attribute__((ext_vector_type(8)));
typedef float f32x4 __attribute__((ext_vector_type(4)));

__device__ __forceinline__ float sigm_f(float x) {
  return RCP(1.0f + __expf(-x));
}
__device__ __forceinline__ float tanh_f(float x) {
  float e = __expf(-2.0f * fabsf(x));
  float t = (1.0f - e) * RCP(1.0f + e);
  return copysignf(t, x);
}

#define KEEP(x) asm volatile("" : "+v"(x))
#define KEEPV(v) do { int4& kr_ = *reinterpret_cast<int4*>(&(v)); \
  KEEP(kr_.x); KEEP(kr_.y); KEEP(kr_.z); KEEP(kr_.w); } while (0)

// Tick barrier WITHOUT the vmcnt(0) drain __syncthreads would impose:
// LDS (h exchange) is ordered by lgkmcnt(0)+s_barrier; global gi-prefetch
// loads and out stores stay in flight across the barrier (lane-private,
// ordered at their USE by compiler-inserted vmcnt waits).
#define TICK_BARRIER() asm volatile("s_waitcnt lgkmcnt(0)\ns_barrier" ::: "memory")

// ---------------- pass 1 (r15, verified): gi0 = X @ W0ih^T + b0ih + act flags ----------------
__global__ __launch_bounds__(256) void gemm_kernel(
    const float* __restrict__ x,     // [B,T,D]
    const float* __restrict__ w0ih,  // [N3,D]
    const float* __restrict__ b0ih,  // [N3]
    float* __restrict__ gi0,         // [B,Tc,N3]
    int* __restrict__ act,           // [T]
    int t0, int Tc) {
  __shared__ _Float16 Xs[64][72];
  __shared__ _Float16 Ws[64][72];
  __shared__ unsigned char sflag[64];

  const int tid = threadIdx.x;
  const int bid = blockIdx.x;
  const int nt = bid % 3;
  const int mt = bid / 3;
  const int tpc = Tc >> 6;
  const int b  = mt / tpc;
  const int tt = mt % tpc;
  const int c0 = nt * 64;

  const int lane = tid & 63;
  const int wid  = tid >> 6;
  const int wm = (wid >> 1) * 32;
  const int wn = (wid & 1) * 32;
  const int l15 = lane & 15;
  const int l4  = lane >> 4;

  const float* xbase = x + ((size_t)b * T_ + t0 + tt * 64) * D_;
  const float* wbase = w0ih + (size_t)c0 * D_;

  const int srow = tid >> 2;
  const int scg  = (tid & 3) << 4;
  const float* xrow = xbase + (size_t)srow * D_;
  const float* wrow = wbase + (size_t)srow * D_;

  f32x4 acc[2][2];
#pragma unroll
  for (int mi = 0; mi < 2; ++mi)
#pragma unroll
    for (int ni = 0; ni < 2; ++ni) {
      acc[mi][ni].x = 0.f; acc[mi][ni].y = 0.f;
      acc[mi][ni].z = 0.f; acc[mi][ni].w = 0.f;
    }

  bool f = false;

  for (int kt = 0; kt < D_ / 64; ++kt) {
    const int k0 = kt * 64 + scg;
    float4 xa = *(const float4*)&xrow[k0];
    float4 xb = *(const float4*)&xrow[k0 + 4];
    float4 xc = *(const float4*)&xrow[k0 + 8];
    float4 xd = *(const float4*)&xrow[k0 + 12];
    float4 wa = *(const float4*)&wrow[k0];
    float4 wb = *(const float4*)&wrow[k0 + 4];
    float4 wc = *(const float4*)&wrow[k0 + 8];
    float4 wd = *(const float4*)&wrow[k0 + 12];
    f |= (xa.x != 0.f) | (xa.y != 0.f) | (xa.z != 0.f) | (xa.w != 0.f) |
         (xb.x != 0.f) | (xb.y != 0.f) | (xb.z != 0.f) | (xb.w != 0.f) |
         (xc.x != 0.f) | (xc.y != 0.f) | (xc.z != 0.f) | (xc.w != 0.f) |
         (xd.x != 0.f) | (xd.y != 0.f) | (xd.z != 0.f) | (xd.w != 0.f);
    __syncthreads();
    {
      f16x8 p0 = {(_Float16)xa.x, (_Float16)xa.y, (_Float16)xa.z, (_Float16)xa.w,
                  (_Float16)xb.x, (_Float16)xb.y, (_Float16)xb.z, (_Float16)xb.w};
      f16x8 p1 = {(_Float16)xc.x, (_Float16)xc.y, (_Float16)xc.z, (_Float16)xc.w,
                  (_Float16)xd.x, (_Float16)xd.y, (_Float16)xd.z, (_Float16)xd.w};
      *(f16x8*)&Xs[srow][scg] = p0;
      *(f16x8*)&Xs[srow][scg + 8] = p1;
      f16x8 q0 = {(_Float16)wa.x, (_Float16)wa.y, (_Float16)wa.z, (_Float16)wa.w,
                  (_Float16)wb.x, (_Float16)wb.y, (_Float16)wb.z, (_Float16)wb.w};
      f16x8 q1 = {(_Float16)wc.x, (_Float16)wc.y, (_Float16)wc.z, (_Float16)wc.w,
                  (_Float16)wd.x, (_Float16)wd.y, (_Float16)wd.z, (_Float16)wd.w};
      *(f16x8*)&Ws[srow][scg] = q0;
      *(f16x8*)&Ws[srow][scg + 8] = q1;
    }
    __syncthreads();
#pragma unroll
    for (int ks = 0; ks < 2; ++ks) {
      const int kb = ks * 32 + l4 * 8;
      f16x8 a0 = *(const f16x8*)&Xs[wm + l15][kb];
      f16x8 a1 = *(const f16x8*)&Xs[wm + 16 + l15][kb];
      f16x8 b0 = *(const f16x8*)&Ws[wn + l15][kb];
      f16x8 b1 = *(const f16x8*)&Ws[wn + 16 + l15][kb];
      acc[0][0] = __builtin_amdgcn_mfma_f32_16x16x32_f16(a0, b0, acc[0][0], 0, 0, 0);
      acc[0][1] = __builtin_amdgcn_mfma_f32_16x16x32_f16(a0, b1, acc[0][1], 0, 0, 0);
      acc[1][0] = __builtin_amdgcn_mfma_f32_16x16x32_f16(a1, b0, acc[1][0], 0, 0, 0);
      acc[1][1] = __builtin_amdgcn_mfma_f32_16x16x32_f16(a1, b1, acc[1][1], 0, 0, 0);
    }
  }

  const float bias0 = b0ih[c0 + wn + l15];
  const float bias1 = b0ih[c0 + wn + 16 + l15];
  const size_t rowbase = (size_t)b * Tc + tt * 64;
#pragma unroll
  for (int mi = 0; mi < 2; ++mi)
#pragma unroll
    for (int r = 0; r < 4; ++r) {
      const int m = wm + mi * 16 + l4 * 4 + r;
      float* orow = &gi0[(rowbase + m) * N3 + c0 + wn];
      orow[l15]      = acc[mi][0][r] + bias0;
      orow[16 + l15] = acc[mi][1][r] + bias1;
    }

  if (tid < 64) sflag[tid] = 0;
  __syncthreads();
  if (f) sflag[srow] = 1;
  __syncthreads();
  if (tid < 64 && sflag[tid]) act[t0 + tt * 64 + tid] = 1;
}

// A-fragment read from swizzled h-tile [MB][64] f16: row = l&15, chunk c.
__device__ __forceinline__ f16x8 loadA(const _Float16* hb, int row, int c) {
  int pc = c ^ (row & 7);
  return *(const f16x8*)&hb[row * 64 + 8 * pc];
}
#define MFMA16(A, Bv, C) __builtin_amdgcn_mfma_f32_16x16x32_f16(A, Bv, C, 0, 0, 0)

// ------------- pass 2: MFMA layer-pipelined scan, 8 blocks x 16 batch rows -------------
// r16 structure (verified correct, absmax 0.00195) with the r17 fix: the tick
// barrier no longer drains vmcnt (TICK_BARRIER), and grp2's out-store is
// deferred one tick and issued at tick TOP (prev hreg), so global latency
// overlaps the tick instead of serializing before the barrier.
__global__ __launch_bounds__(768, 3) void scan_kernel(
    const float* __restrict__ gi0,   // [B,Tc,N3]
    const float* __restrict__ w0hh, const float* __restrict__ w1ih,
    const float* __restrict__ w1hh, const float* __restrict__ w2ih,
    const float* __restrict__ w2hh,
    const float* __restrict__ b0hh, const float* __restrict__ b1ih,
    const float* __restrict__ b1hh, const float* __restrict__ b2ih,
    const float* __restrict__ b2hh,
    const int* __restrict__ act,     // [T]
    float* __restrict__ hstate,      // [3,B,H]
    float* __restrict__ out,         // [B,T,H]
    int t0, int Tc) {
  const int b0 = blockIdx.x * MB;
  const int tid = threadIdx.x;
  const int lane = tid & 63;
  const int wave = tid >> 6;        // 0..11
  const int grp = wave >> 2;        // layer 0..2
  const int w   = wave & 3;         // col-group
  const int l15 = lane & 15;
  const int l4  = lane >> 4;        // 0..3
  const int j   = 16 * w + l15;     // unit/col id [0,64)

  __shared__ __align__(16) _Float16 s_h[3][2][MB][64];  // 12KB, chunk-swizzled
  __shared__ int s_act[T_];

  for (int i = tid; i < Tc; i += 768) s_act[i] = act[t0 + i];

  // ---- B-fragments (weights) -> registers, f32->f16 ----
  const float* matIH = (grp == 1) ? w1ih : (grp == 2) ? w2ih : w0hh;  // grp0 dummy
  const float* matHH = (grp == 0) ? w0hh : (grp == 1) ? w1hh : w2hh;
  f16x8 bf[2][3][2];   // [0=ih,1=hh][gate][kstep]
#pragma unroll
  for (int m2 = 0; m2 < 2; ++m2) {
    const float* mp = m2 ? matHH : matIH;
#pragma unroll
    for (int g = 0; g < 3; ++g)
#pragma unroll
      for (int ks = 0; ks < 2; ++ks) {
        const float* src = mp + (size_t)(64 * g + j) * H_ + l4 * 8 + 32 * ks;
        f16x8 v;
#pragma unroll
        for (int q = 0; q < 8; ++q) v[q] = (_Float16)src[q];
        bf[m2][g][ks] = v;
      }
  }
#pragma unroll
  for (int m2 = 0; m2 < 2; ++m2)
#pragma unroll
    for (int g = 0; g < 3; ++g)
#pragma unroll
      for (int ks = 0; ks < 2; ++ks) KEEPV(bf[m2][g][ks]);

  // ---- biases (per lane col j) ----
  float bR, bZ, biN, bhN;
  if (grp == 0) {
    bR = b0hh[j]; bZ = b0hh[j + 64]; biN = 0.f; bhN = b0hh[j + 128];
  } else if (grp == 1) {
    bR = b1ih[j] + b1hh[j]; bZ = b1ih[j + 64] + b1hh[j + 64];
    biN = b1ih[j + 128]; bhN = b1hh[j + 128];
  } else {
    bR = b2ih[j] + b2hh[j]; bZ = b2ih[j + 64] + b2hh[j + 64];
    biN = b2ih[j + 128]; bhN = b2hh[j + 128];
  }

  // ---- state: lane owns (rows l4*4+r, col j) of its layer ----
  float hreg[4];
#pragma unroll
  for (int r = 0; r < 4; ++r) {
    int m = l4 * 4 + r;
    float v = (t0 == 0) ? 0.f
                        : hstate[grp * B_ * H_ + (size_t)(b0 + m) * H_ + j];
    hreg[r] = v;
    int pc = (j >> 3) ^ (m & 7);
    s_h[grp][0][m][8 * pc + (j & 7)] = (_Float16)v;
    s_h[grp][1][m][8 * pc + (j & 7)] = (_Float16)v;
  }

  // ---- grp0: gi registers (prefetched per tick) ----
  float giv[3][4];
  if (grp == 0) {
#pragma unroll
    for (int g = 0; g < 3; ++g)
#pragma unroll
      for (int r = 0; r < 4; ++r)
        giv[g][r] = gi0[((size_t)(b0 + l4 * 4 + r) * Tc) * N3 + 64 * g + j];
  }

  __syncthreads();   // initial full barrier (covers weight/state staging)

  const f32x4 zz = {0.f, 0.f, 0.f, 0.f};
  bool aprev = false;

  for (int i = 0; i < Tc + 3; ++i) {
    const int p = i & 1;
    if (grp == 0) {
      if (i < Tc) {
        const _Float16* hb = &s_h[0][p ^ 1][0][0];
        f16x8 a0 = loadA(hb, l15, l4);
        f16x8 a1 = loadA(hb, l15, l4 + 4);
        f32x4 aR = MFMA16(a0, bf[1][0][0], zz);
        aR = MFMA16(a1, bf[1][0][1], aR);
        f32x4 aZ = MFMA16(a0, bf[1][1][0], zz);
        aZ = MFMA16(a1, bf[1][1][1], aZ);
        f32x4 aN = MFMA16(a0, bf[1][2][0], zz);
        aN = MFMA16(a1, bf[1][2][1], aN);
        bool a = (s_act[i] != 0);
#pragma unroll
        for (int r = 0; r < 4; ++r) {
          int m = l4 * 4 + r;
          float R = sigm_f(giv[0][r] + aR[r] + bR);
          float Z = sigm_f(giv[1][r] + aZ[r] + bZ);
          float N = tanh_f(giv[2][r] + R * (aN[r] + bhN));
          float hn = (1.f - Z) * N + Z * hreg[r];
          hreg[r] = a ? hn : hreg[r];
          int pc = (j >> 3) ^ (m & 7);
          s_h[0][p][m][8 * pc + (j & 7)] = (_Float16)hreg[r];
        }
        int tn = (i + 1 < Tc) ? i + 1 : Tc - 1;
#pragma unroll
        for (int g = 0; g < 3; ++g)
#pragma unroll
          for (int r = 0; r < 4; ++r)
            giv[g][r] = gi0[((size_t)(b0 + l4 * 4 + r) * Tc + tn) * N3 + 64 * g + j];
      }
    } else if (grp == 1) {
      if (i >= 1 && i <= Tc) {
        const _Float16* hp = &s_h[0][p ^ 1][0][0];
        const _Float16* hs = &s_h[1][p ^ 1][0][0];
        f16x8 p0 = loadA(hp, l15, l4), p1 = loadA(hp, l15, l4 + 4);
        f16x8 s0 = loadA(hs, l15, l4), s1 = loadA(hs, l15, l4 + 4);
        f32x4 aR = MFMA16(p0, bf[0][0][0], zz);
        aR = MFMA16(p1, bf[0][0][1], aR);
        aR = MFMA16(s0, bf[1][0][0], aR);
        aR = MFMA16(s1, bf[1][0][1], aR);
        f32x4 aZ = MFMA16(p0, bf[0][1][0], zz);
        aZ = MFMA16(p1, bf[0][1][1], aZ);
        aZ = MFMA16(s0, bf[1][1][0], aZ);
        aZ = MFMA16(s1, bf[1][1][1], aZ);
        f32x4 aiN = MFMA16(p0, bf[0][2][0], zz);
        aiN = MFMA16(p1, bf[0][2][1], aiN);
        f32x4 ahN = MFMA16(s0, bf[1][2][0], zz);
        ahN = MFMA16(s1, bf[1][2][1], ahN);
        bool a = (s_act[i - 1] != 0);
#pragma unroll
        for (int r = 0; r < 4; ++r) {
          int m = l4 * 4 + r;
          float R = sigm_f(aR[r] + bR);
          float Z = sigm_f(aZ[r] + bZ);
          float N = tanh_f(aiN[r] + biN + R * (ahN[r] + bhN));
          float hn = (1.f - Z) * N + Z * hreg[r];
          hreg[r] = a ? hn : hreg[r];
          int pc = (j >> 3) ^ (m & 7);
          s_h[1][p][m][8 * pc + (j & 7)] = (_Float16)hreg[r];
        }
      }
    } else {
      // ---- early store: PREVIOUS step's h (full tick to drain) ----
      if (i >= 3 && i <= Tc + 2) {
        int tprev = t0 + i - 3;
#pragma unroll
        for (int r = 0; r < 4; ++r) {
          int m = l4 * 4 + r;
          out[((size_t)(b0 + m) * T_ + tprev) * H_ + j] = aprev ? hreg[r] : 0.f;
        }
      }
      if (i >= 2 && i <= Tc + 1) {
        const _Float16* hp = &s_h[1][p ^ 1][0][0];
        const _Float16* hs = &s_h[2][p ^ 1][0][0];
        f16x8 p0 = loadA(hp, l15, l4), p1 = loadA(hp, l15, l4 + 4);
        f16x8 s0 = loadA(hs, l15, l4), s1 = loadA(hs, l15, l4 + 4);
        f32x4 aR = MFMA16(p0, bf[0][0][0], zz);
        aR = MFMA16(p1, bf[0][0][1], aR);
        aR = MFMA16(s0, bf[1][0][0], aR);
        aR = MFMA16(s1, bf[1][0][1], aR);
        f32x4 aZ = MFMA16(p0, bf[0][1][0], zz);
        aZ = MFMA16(p1, bf[0][1][1], aZ);
        aZ = MFMA16(s0, bf[1][1][0], aZ);
        aZ = MFMA16(s1, bf[1][1][1], aZ);
        f32x4 aiN = MFMA16(p0, bf[0][2][0], zz);
        aiN = MFMA16(p1, bf[0][2][1], aiN);
        f32x4 ahN = MFMA16(s0, bf[1][2][0], zz);
        ahN = MFMA16(s1, bf[1][2][1], ahN);
        bool a = (s_act[i - 2] != 0);
#pragma unroll
        for (int r = 0; r < 4; ++r) {
          int m = l4 * 4 + r;
          float R = sigm_f(aR[r] + bR);
          float Z = sigm_f(aZ[r] + bZ);
          float N = tanh_f(aiN[r] + biN + R * (ahN[r] + bhN));
          float hn = (1.f - Z) * N + Z * hreg[r];
          hreg[r] = a ? hn : hreg[r];
          int pc = (j >> 3) ^ (m & 7);
          s_h[2][p][m][8 * pc + (j & 7)] = (_Float16)hreg[r];
        }
        aprev = a;
      }
    }
    TICK_BARRIER();   // lgkmcnt(0)+s_barrier only: NO vmcnt drain per tick
  }

#pragma unroll
  for (int r = 0; r < 4; ++r)
    hstate[grp * B_ * H_ + (size_t)(b0 + l4 * 4 + r) * H_ + j] = hreg[r];
}

extern "C" void kernel_launch(void* const* d_in, const int* in_sizes, int n_in,
                              void* d_out, int out_size, void* d_ws, size_t ws_size,
                              hipStream_t stream) {
  const float* x    = (const float*)d_in[0];
  const float* w0ih = (const float*)d_in[1];
  const float* w0hh = (const float*)d_in[2];
  const float* b0ih = (const float*)d_in[3];
  const float* b0hh = (const float*)d_in[4];
  const float* w1ih = (const float*)d_in[5];
  const float* w1hh = (const float*)d_in[6];
  const float* b1ih = (const float*)d_in[7];
  const float* b1hh = (const float*)d_in[8];
  const float* w2ih = (const float*)d_in[9];
  const float* w2hh = (const float*)d_in[10];
  const float* b2ih = (const float*)d_in[11];
  const float* b2hh = (const float*)d_in[12];
  float* out = (float*)d_out;

  char* p = (char*)d_ws;
  int* act      = (int*)p;    p += 4096;
  float* hstate = (float*)p;  p += (size_t)3 * B_ * H_ * 4;
  size_t fixed = (size_t)(p - (char*)d_ws);

  int Tc = T_;
  while (Tc > 64 && fixed + (size_t)B_ * Tc * N3 * 4 > ws_size) Tc >>= 1;
  float* gi0 = (float*)p;

  hipMemsetAsync(act, 0, T_ * sizeof(int), stream);
  for (int t0 = 0; t0 < T_; t0 += Tc) {
    gemm_kernel<<<dim3(B_ * (Tc / 64) * 3), 256, 0, stream>>>(
        x, w0ih, b0ih, gi0, act, t0, Tc);
    scan_kernel<<<B_ / MB, 768, 0, stream>>>(
        gi0, w0hh, w1ih, w1hh, w2ih, w2hh,
        b0hh, b1ih, b1hh, b2ih, b2hh, act, hstate, out, t0, Tc);
  }
}

// Round 18
// 533.968 us; speedup vs baseline: 1.1168x; 1.0997x over previous
//
#include <hip/hip_runtime.h>

#define B_ 128
#define T_ 512
#define D_ 512
#define H_ 64
#define N3 192   // 3*H
#define MB 16    // batch rows per scan block

#if __has_builtin(__builtin_amdgcn_rcpf)
#define RCP(x) __builtin_amdgcn_rcpf(x)
#else
#define RCP(x) (1.0f / (x))
#endif

typedef _Float16 f16x8 __attribute__((ext_vector_type(8)));
typedef float f32x4 __attribute__((ext_vector_type(4)));

__device__ __forceinline__ float sigm_f(float x) {
  return RCP(1.0f + __expf(-x));
}
__device__ __forceinline__ float tanh_f(float x) {
  float e = __expf(-2.0f * fabsf(x));
  float t = (1.0f - e) * RCP(1.0f + e);
  return copysignf(t, x);
}

#define KEEP(x) asm volatile("" : "+v"(x))
#define KEEPV(v) do { int4& kr_ = *reinterpret_cast<int4*>(&(v)); \
  KEEP(kr_.x); KEEP(kr_.y); KEEP(kr_.z); KEEP(kr_.w); } while (0)

// lgkmcnt(0)+s_barrier only (no vmcnt drain): LDS h-exchange ordered; global
// gi loads / out stores stay in flight across the barrier.
#define TICK_BARRIER() asm volatile("s_waitcnt lgkmcnt(0)\ns_barrier" ::: "memory")

// ---------------- pass 1 (r15 MFMA gemm + r18 bias fold): gi0 = X @ W0ih^T + bias ----------------
// bias fold: cols 0..127 (R,Z) get b0ih + b0hh; cols 128..191 (N) get b0ih
// only (b0hh_N enters via R*(...) in the scan).
__global__ __launch_bounds__(256) void gemm_kernel(
    const float* __restrict__ x,     // [B,T,D]
    const float* __restrict__ w0ih,  // [N3,D]
    const float* __restrict__ b0ih,  // [N3]
    const float* __restrict__ b0hh,  // [N3]
    float* __restrict__ gi0,         // [B,Tc,N3]
    int* __restrict__ act,           // [T]
    int t0, int Tc) {
  __shared__ _Float16 Xs[64][72];
  __shared__ _Float16 Ws[64][72];
  __shared__ unsigned char sflag[64];

  const int tid = threadIdx.x;
  const int bid = blockIdx.x;
  const int nt = bid % 3;
  const int mt = bid / 3;
  const int tpc = Tc >> 6;
  const int b  = mt / tpc;
  const int tt = mt % tpc;
  const int c0 = nt * 64;

  const int lane = tid & 63;
  const int wid  = tid >> 6;
  const int wm = (wid >> 1) * 32;
  const int wn = (wid & 1) * 32;
  const int l15 = lane & 15;
  const int l4  = lane >> 4;

  const float* xbase = x + ((size_t)b * T_ + t0 + tt * 64) * D_;
  const float* wbase = w0ih + (size_t)c0 * D_;

  const int srow = tid >> 2;
  const int scg  = (tid & 3) << 4;
  const float* xrow = xbase + (size_t)srow * D_;
  const float* wrow = wbase + (size_t)srow * D_;

  f32x4 acc[2][2];
#pragma unroll
  for (int mi = 0; mi < 2; ++mi)
#pragma unroll
    for (int ni = 0; ni < 2; ++ni) {
      acc[mi][ni].x = 0.f; acc[mi][ni].y = 0.f;
      acc[mi][ni].z = 0.f; acc[mi][ni].w = 0.f;
    }

  bool f = false;

  for (int kt = 0; kt < D_ / 64; ++kt) {
    const int k0 = kt * 64 + scg;
    float4 xa = *(const float4*)&xrow[k0];
    float4 xb = *(const float4*)&xrow[k0 + 4];
    float4 xc = *(const float4*)&xrow[k0 + 8];
    float4 xd = *(const float4*)&xrow[k0 + 12];
    float4 wa = *(const float4*)&wrow[k0];
    float4 wb = *(const float4*)&wrow[k0 + 4];
    float4 wc = *(const float4*)&wrow[k0 + 8];
    float4 wd = *(const float4*)&wrow[k0 + 12];
    f |= (xa.x != 0.f) | (xa.y != 0.f) | (xa.z != 0.f) | (xa.w != 0.f) |
         (xb.x != 0.f) | (xb.y != 0.f) | (xb.z != 0.f) | (xb.w != 0.f) |
         (xc.x != 0.f) | (xc.y != 0.f) | (xc.z != 0.f) | (xc.w != 0.f) |
         (xd.x != 0.f) | (xd.y != 0.f) | (xd.z != 0.f) | (xd.w != 0.f);
    __syncthreads();
    {
      f16x8 p0 = {(_Float16)xa.x, (_Float16)xa.y, (_Float16)xa.z, (_Float16)xa.w,
                  (_Float16)xb.x, (_Float16)xb.y, (_Float16)xb.z, (_Float16)xb.w};
      f16x8 p1 = {(_Float16)xc.x, (_Float16)xc.y, (_Float16)xc.z, (_Float16)xc.w,
                  (_Float16)xd.x, (_Float16)xd.y, (_Float16)xd.z, (_Float16)xd.w};
      *(f16x8*)&Xs[srow][scg] = p0;
      *(f16x8*)&Xs[srow][scg + 8] = p1;
      f16x8 q0 = {(_Float16)wa.x, (_Float16)wa.y, (_Float16)wa.z, (_Float16)wa.w,
                  (_Float16)wb.x, (_Float16)wb.y, (_Float16)wb.z, (_Float16)wb.w};
      f16x8 q1 = {(_Float16)wc.x, (_Float16)wc.y, (_Float16)wc.z, (_Float16)wc.w,
                  (_Float16)wd.x, (_Float16)wd.y, (_Float16)wd.z, (_Float16)wd.w};
      *(f16x8*)&Ws[srow][scg] = q0;
      *(f16x8*)&Ws[srow][scg + 8] = q1;
    }
    __syncthreads();
#pragma unroll
    for (int ks = 0; ks < 2; ++ks) {
      const int kb = ks * 32 + l4 * 8;
      f16x8 a0 = *(const f16x8*)&Xs[wm + l15][kb];
      f16x8 a1 = *(const f16x8*)&Xs[wm + 16 + l15][kb];
      f16x8 b0 = *(const f16x8*)&Ws[wn + l15][kb];
      f16x8 b1 = *(const f16x8*)&Ws[wn + 16 + l15][kb];
      acc[0][0] = __builtin_amdgcn_mfma_f32_16x16x32_f16(a0, b0, acc[0][0], 0, 0, 0);
      acc[0][1] = __builtin_amdgcn_mfma_f32_16x16x32_f16(a0, b1, acc[0][1], 0, 0, 0);
      acc[1][0] = __builtin_amdgcn_mfma_f32_16x16x32_f16(a1, b0, acc[1][0], 0, 0, 0);
      acc[1][1] = __builtin_amdgcn_mfma_f32_16x16x32_f16(a1, b1, acc[1][1], 0, 0, 0);
    }
  }

  const int cA = c0 + wn + l15;
  const int cB = c0 + wn + 16 + l15;
  const float bias0 = b0ih[cA] + ((cA < 128) ? b0hh[cA] : 0.f);
  const float bias1 = b0ih[cB] + ((cB < 128) ? b0hh[cB] : 0.f);
  const size_t rowbase = (size_t)b * Tc + tt * 64;
#pragma unroll
  for (int mi = 0; mi < 2; ++mi)
#pragma unroll
    for (int r = 0; r < 4; ++r) {
      const int m = wm + mi * 16 + l4 * 4 + r;
      float* orow = &gi0[(rowbase + m) * N3 + c0 + wn];
      orow[l15]      = acc[mi][0][r] + bias0;
      orow[16 + l15] = acc[mi][1][r] + bias1;
    }

  if (tid < 64) sflag[tid] = 0;
  __syncthreads();
  if (f) sflag[srow] = 1;
  __syncthreads();
  if (tid < 64 && sflag[tid]) act[t0 + tt * 64 + tid] = 1;
}

// A-fragment read from swizzled h-tile [MB][64] f16: row = l&15, chunk c.
__device__ __forceinline__ f16x8 loadA(const _Float16* hb, int row, int c) {
  int pc = c ^ (row & 7);
  return *(const f16x8*)&hb[row * 64 + 8 * pc];
}
#define MFMA16(A, Bv, C) __builtin_amdgcn_mfma_f32_16x16x32_f16(A, Bv, C, 0, 0, 0)

// ------------- pass 2: MFMA layer-pipelined scan (r17 sync) + r18 VALU diet -------------
// r17 diagnosis: 8 active CUs at ~67% VALU-busy -> VALU-issue-bound. Cuts:
// (1) gi and biases ride the MFMA C operand (gates read acc directly);
// (2) incremental gi row-pointers (no 64-bit addr math per tick);
// (3) h' = fma(Z, h-N, N); unroll-2 folds parity into imm offsets.
__global__ __launch_bounds__(768, 3) void scan_kernel(
    const float* __restrict__ gi0,   // [B,Tc,N3]
    const float* __restrict__ w0hh, const float* __restrict__ w1ih,
    const float* __restrict__ w1hh, const float* __restrict__ w2ih,
    const float* __restrict__ w2hh,
    const float* __restrict__ b0hh, const float* __restrict__ b1ih,
    const float* __restrict__ b1hh, const float* __restrict__ b2ih,
    const float* __restrict__ b2hh,
    const int* __restrict__ act,     // [T]
    float* __restrict__ hstate,      // [3,B,H]
    float* __restrict__ out,         // [B,T,H]
    int t0, int Tc) {
  const int b0 = blockIdx.x * MB;
  const int tid = threadIdx.x;
  const int lane = tid & 63;
  const int wave = tid >> 6;        // 0..11
  const int grp = wave >> 2;        // layer 0..2
  const int w   = wave & 3;         // col-group
  const int l15 = lane & 15;
  const int l4  = lane >> 4;        // 0..3
  const int j   = 16 * w + l15;     // unit/col id [0,64)

  __shared__ __align__(16) _Float16 s_h[3][2][MB][64];  // 12KB, chunk-swizzled
  __shared__ int s_act[T_];

  for (int i = tid; i < Tc; i += 768) s_act[i] = act[t0 + i];

  // ---- B-fragments (weights) -> registers, f32->f16 ----
  const float* matIH = (grp == 1) ? w1ih : (grp == 2) ? w2ih : w0hh;  // grp0 dummy
  const float* matHH = (grp == 0) ? w0hh : (grp == 1) ? w1hh : w2hh;
  f16x8 bf[2][3][2];   // [0=ih,1=hh][gate][kstep]
#pragma unroll
  for (int m2 = 0; m2 < 2; ++m2) {
    const float* mp = m2 ? matHH : matIH;
#pragma unroll
    for (int g = 0; g < 3; ++g)
#pragma unroll
      for (int ks = 0; ks < 2; ++ks) {
        const float* src = mp + (size_t)(64 * g + j) * H_ + l4 * 8 + 32 * ks;
        f16x8 v;
#pragma unroll
        for (int q = 0; q < 8; ++q) v[q] = (_Float16)src[q];
        bf[m2][g][ks] = v;
      }
  }
#pragma unroll
  for (int m2 = 0; m2 < 2; ++m2)
#pragma unroll
    for (int g = 0; g < 3; ++g)
#pragma unroll
      for (int ks = 0; ks < 2; ++ks) KEEPV(bf[m2][g][ks]);

  // ---- bias C-seeds (per lane col j), broadcast to f32x4 ----
  // grp0: R/Z biases folded into gemm; only bhN needed here.
  float bR = 0.f, bZ = 0.f, biN = 0.f, bhN;
  if (grp == 0) {
    bhN = b0hh[j + 128];
  } else if (grp == 1) {
    bR = b1ih[j] + b1hh[j]; bZ = b1ih[j + 64] + b1hh[j + 64];
    biN = b1ih[j + 128]; bhN = b1hh[j + 128];
  } else {
    bR = b2ih[j] + b2hh[j]; bZ = b2ih[j + 64] + b2hh[j + 64];
    biN = b2ih[j + 128]; bhN = b2hh[j + 128];
  }
  const f32x4 bR4  = {bR, bR, bR, bR};
  const f32x4 bZ4  = {bZ, bZ, bZ, bZ};
  const f32x4 biN4 = {biN, biN, biN, biN};
  const f32x4 bhN4 = {bhN, bhN, bhN, bhN};

  // ---- state: lane owns (rows l4*4+r, col j) of its layer ----
  float hreg[4];
#pragma unroll
  for (int r = 0; r < 4; ++r) {
    int m = l4 * 4 + r;
    float v = (t0 == 0) ? 0.f
                        : hstate[grp * B_ * H_ + (size_t)(b0 + m) * H_ + j];
    hreg[r] = v;
    int pc = (j >> 3) ^ (m & 7);
    s_h[grp][0][m][8 * pc + (j & 7)] = (_Float16)v;
    s_h[grp][1][m][8 * pc + (j & 7)] = (_Float16)v;
  }

  // ---- grp0: incremental gi row-pointers + initial load ----
  const float* gp0 = gi0 + ((size_t)(b0 + l4 * 4 + 0) * Tc) * N3 + j;
  const float* gp1 = gi0 + ((size_t)(b0 + l4 * 4 + 1) * Tc) * N3 + j;
  const float* gp2 = gi0 + ((size_t)(b0 + l4 * 4 + 2) * Tc) * N3 + j;
  const float* gp3 = gi0 + ((size_t)(b0 + l4 * 4 + 3) * Tc) * N3 + j;
  f32x4 giv[3];
  if (grp == 0) {
#pragma unroll
    for (int g = 0; g < 3; ++g) {
      giv[g][0] = gp0[64 * g]; giv[g][1] = gp1[64 * g];
      giv[g][2] = gp2[64 * g]; giv[g][3] = gp3[64 * g];
    }
  }

  __syncthreads();   // initial full barrier (covers weight/state staging)

  bool aprev = false;

#pragma unroll 2
  for (int i = 0; i < Tc + 3; ++i) {
    const int p = i & 1;
    if (grp == 0) {
      if (i < Tc) {
        const _Float16* hb = &s_h[0][p ^ 1][0][0];
        f16x8 a0 = loadA(hb, l15, l4);
        f16x8 a1 = loadA(hb, l15, l4 + 4);
        // C-seeds: R/Z = gi (bias pre-folded by gemm); N = bhN broadcast.
        f32x4 aR = MFMA16(a0, bf[1][0][0], giv[0]);
        aR = MFMA16(a1, bf[1][0][1], aR);
        f32x4 aZ = MFMA16(a0, bf[1][1][0], giv[1]);
        aZ = MFMA16(a1, bf[1][1][1], aZ);
        f32x4 aN = MFMA16(a0, bf[1][2][0], bhN4);
        aN = MFMA16(a1, bf[1][2][1], aN);
        bool a = (s_act[i] != 0);
#pragma unroll
        for (int r = 0; r < 4; ++r) {
          int m = l4 * 4 + r;
          float R = sigm_f(aR[r]);
          float Z = sigm_f(aZ[r]);
          float N = tanh_f(fmaf(R, aN[r], giv[2][r]));
          float hn = fmaf(Z, hreg[r] - N, N);
          hreg[r] = a ? hn : hreg[r];
          int pc = (j >> 3) ^ (m & 7);
          s_h[0][p][m][8 * pc + (j & 7)] = (_Float16)hreg[r];
        }
        if (i + 1 < Tc) { gp0 += N3; gp1 += N3; gp2 += N3; gp3 += N3; }
#pragma unroll
        for (int g = 0; g < 3; ++g) {
          giv[g][0] = gp0[64 * g]; giv[g][1] = gp1[64 * g];
          giv[g][2] = gp2[64 * g]; giv[g][3] = gp3[64 * g];
        }
      }
    } else if (grp == 1) {
      if (i >= 1 && i <= Tc) {
        const _Float16* hp = &s_h[0][p ^ 1][0][0];
        const _Float16* hs = &s_h[1][p ^ 1][0][0];
        f16x8 p0 = loadA(hp, l15, l4), p1 = loadA(hp, l15, l4 + 4);
        f16x8 s0 = loadA(hs, l15, l4), s1 = loadA(hs, l15, l4 + 4);
        f32x4 aR = MFMA16(p0, bf[0][0][0], bR4);
        aR = MFMA16(p1, bf[0][0][1], aR);
        aR = MFMA16(s0, bf[1][0][0], aR);
        aR = MFMA16(s1, bf[1][0][1], aR);
        f32x4 aZ = MFMA16(p0, bf[0][1][0], bZ4);
        aZ = MFMA16(p1, bf[0][1][1], aZ);
        aZ = MFMA16(s0, bf[1][1][0], aZ);
        aZ = MFMA16(s1, bf[1][1][1], aZ);
        f32x4 aiN = MFMA16(p0, bf[0][2][0], biN4);
        aiN = MFMA16(p1, bf[0][2][1], aiN);
        f32x4 ahN = MFMA16(s0, bf[1][2][0], bhN4);
        ahN = MFMA16(s1, bf[1][2][1], ahN);
        bool a = (s_act[i - 1] != 0);
#pragma unroll
        for (int r = 0; r < 4; ++r) {
          int m = l4 * 4 + r;
          float R = sigm_f(aR[r]);
          float Z = sigm_f(aZ[r]);
          float N = tanh_f(fmaf(R, ahN[r], aiN[r]));
          float hn = fmaf(Z, hreg[r] - N, N);
          hreg[r] = a ? hn : hreg[r];
          int pc = (j >> 3) ^ (m & 7);
          s_h[1][p][m][8 * pc + (j & 7)] = (_Float16)hreg[r];
        }
      }
    } else {
      // ---- early store: PREVIOUS step's h (full tick to drain) ----
      if (i >= 3 && i <= Tc + 2) {
        int tprev = t0 + i - 3;
#pragma unroll
        for (int r = 0; r < 4; ++r) {
          int m = l4 * 4 + r;
          out[((size_t)(b0 + m) * T_ + tprev) * H_ + j] = aprev ? hreg[r] : 0.f;
        }
      }
      if (i >= 2 && i <= Tc + 1) {
        const _Float16* hp = &s_h[1][p ^ 1][0][0];
        const _Float16* hs = &s_h[2][p ^ 1][0][0];
        f16x8 p0 = loadA(hp, l15, l4), p1 = loadA(hp, l15, l4 + 4);
        f16x8 s0 = loadA(hs, l15, l4), s1 = loadA(hs, l15, l4 + 4);
        f32x4 aR = MFMA16(p0, bf[0][0][0], bR4);
        aR = MFMA16(p1, bf[0][0][1], aR);
        aR = MFMA16(s0, bf[1][0][0], aR);
        aR = MFMA16(s1, bf[1][0][1], aR);
        f32x4 aZ = MFMA16(p0, bf[0][1][0], bZ4);
        aZ = MFMA16(p1, bf[0][1][1], aZ);
        aZ = MFMA16(s0, bf[1][1][0], aZ);
        aZ = MFMA16(s1, bf[1][1][1], aZ);
        f32x4 aiN = MFMA16(p0, bf[0][2][0], biN4);
        aiN = MFMA16(p1, bf[0][2][1], aiN);
        f32x4 ahN = MFMA16(s0, bf[1][2][0], bhN4);
        ahN = MFMA16(s1, bf[1][2][1], ahN);
        bool a = (s_act[i - 2] != 0);
#pragma unroll
        for (int r = 0; r < 4; ++r) {
          int m = l4 * 4 + r;
          float R = sigm_f(aR[r]);
          float Z = sigm_f(aZ[r]);
          float N = tanh_f(fmaf(R, ahN[r], aiN[r]));
          float hn = fmaf(Z, hreg[r] - N, N);
          hreg[r] = a ? hn : hreg[r];
          int pc = (j >> 3) ^ (m & 7);
          s_h[2][p][m][8 * pc + (j & 7)] = (_Float16)hreg[r];
        }
        aprev = a;
      }
    }
    TICK_BARRIER();   // lgkmcnt(0)+s_barrier only
  }

#pragma unroll
  for (int r = 0; r < 4; ++r)
    hstate[grp * B_ * H_ + (size_t)(b0 + l4 * 4 + r) * H_ + j] = hreg[r];
}

extern "C" void kernel_launch(void* const* d_in, const int* in_sizes, int n_in,
                              void* d_out, int out_size, void* d_ws, size_t ws_size,
                              hipStream_t stream) {
  const float* x    = (const float*)d_in[0];
  const float* w0ih = (const float*)d_in[1];
  const float* w0hh = (const float*)d_in[2];
  const float* b0ih = (const float*)d_in[3];
  const float* b0hh = (const float*)d_in[4];
  const float* w1ih = (const float*)d_in[5];
  const float* w1hh = (const float*)d_in[6];
  const float* b1ih = (const float*)d_in[7];
  const float* b1hh = (const float*)d_in[8];
  const float* w2ih = (const float*)d_in[9];
  const float* w2hh = (const float*)d_in[10];
  const float* b2ih = (const float*)d_in[11];
  const float* b2hh = (const float*)d_in[12];
  float* out = (float*)d_out;

  char* p = (char*)d_ws;
  int* act      = (int*)p;    p += 4096;
  float* hstate = (float*)p;  p += (size_t)3 * B_ * H_ * 4;
  size_t fixed = (size_t)(p - (char*)d_ws);

  int Tc = T_;
  while (Tc > 64 && fixed + (size_t)B_ * Tc * N3 * 4 > ws_size) Tc >>= 1;
  float* gi0 = (float*)p;

  hipMemsetAsync(act, 0, T_ * sizeof(int), stream);
  for (int t0 = 0; t0 < T_; t0 += Tc) {
    gemm_kernel<<<dim3(B_ * (Tc / 64) * 3), 256, 0, stream>>>(
        x, w0ih, b0ih, b0hh, gi0, act, t0, Tc);
    scan_kernel<<<B_ / MB, 768, 0, stream>>>(
        gi0, w0hh, w1ih, w1hh, w2ih, w2hh,
        b0hh, b1ih, b1hh, b2ih, b2hh, act, hstate, out, t0, Tc);
  }
}

// Round 19
// 445.905 us; speedup vs baseline: 1.3373x; 1.1975x over previous
//
#include <hip/hip_runtime.h>

#define B_ 128
#define T_ 512
#define D_ 512
#define H_ 64
#define N3 192   // 3*H

#if __has_builtin(__builtin_amdgcn_rcpf)
#define RCP(x) __builtin_amdgcn_rcpf(x)
#else
#define RCP(x) (1.0f / (x))
#endif

typedef _Float16 h2v __attribute__((ext_vector_type(2)));
typedef _Float16 f16x8 __attribute__((ext_vector_type(8)));
typedef float f32x4 __attribute__((ext_vector_type(4)));

__device__ __forceinline__ float sigm_f(float x) {
  return RCP(1.0f + __expf(-x));
}
__device__ __forceinline__ float tanh_f(float x) {
  float e = __expf(-2.0f * fabsf(x));
  float t = (1.0f - e) * RCP(1.0f + e);
  return copysignf(t, x);
}

// DPP lane-group sums (bound_ctrl=1).
template <int CTRL>
__device__ __forceinline__ float dpp_add(float v) {
  int t = __builtin_amdgcn_update_dpp(0, __float_as_int(v), CTRL, 0xF, 0xF, true);
  return v + __int_as_float(t);
}
__device__ __forceinline__ float red2(float v) { return dpp_add<0xB1>(v); }
__device__ __forceinline__ float red4(float v) {
  v = dpp_add<0xB1>(v);
  v = dpp_add<0x4E>(v);
  return v;
}

__device__ __forceinline__ void dot4acc(int4 w, int4 h, float& s0, float& s1) {
  s0 = __builtin_amdgcn_fdot2(__builtin_bit_cast(h2v, w.x),
                              __builtin_bit_cast(h2v, h.x), s0, false);
  s1 = __builtin_amdgcn_fdot2(__builtin_bit_cast(h2v, w.y),
                              __builtin_bit_cast(h2v, h.y), s1, false);
  s0 = __builtin_amdgcn_fdot2(__builtin_bit_cast(h2v, w.z),
                              __builtin_bit_cast(h2v, h.z), s0, false);
  s1 = __builtin_amdgcn_fdot2(__builtin_bit_cast(h2v, w.w),
                              __builtin_bit_cast(h2v, h.w), s1, false);
}
__device__ __forceinline__ void dot8reg(const int* w, int4 a, int4 b,
                                        float& s0, float& s1) {
  s0 = __builtin_amdgcn_fdot2(__builtin_bit_cast(h2v, w[0]),
                              __builtin_bit_cast(h2v, a.x), s0, false);
  s1 = __builtin_amdgcn_fdot2(__builtin_bit_cast(h2v, w[1]),
                              __builtin_bit_cast(h2v, a.y), s1, false);
  s0 = __builtin_amdgcn_fdot2(__builtin_bit_cast(h2v, w[2]),
                              __builtin_bit_cast(h2v, a.z), s0, false);
  s1 = __builtin_amdgcn_fdot2(__builtin_bit_cast(h2v, w[3]),
                              __builtin_bit_cast(h2v, a.w), s1, false);
  s0 = __builtin_amdgcn_fdot2(__builtin_bit_cast(h2v, w[4]),
                              __builtin_bit_cast(h2v, b.x), s0, false);
  s1 = __builtin_amdgcn_fdot2(__builtin_bit_cast(h2v, w[5]),
                              __builtin_bit_cast(h2v, b.y), s1, false);
  s0 = __builtin_amdgcn_fdot2(__builtin_bit_cast(h2v, w[6]),
                              __builtin_bit_cast(h2v, b.z), s0, false);
  s1 = __builtin_amdgcn_fdot2(__builtin_bit_cast(h2v, w[7]),
                              __builtin_bit_cast(h2v, b.w), s1, false);
}

#define KEEP(x) asm volatile("" : "+v"(x))

// lgkmcnt(0)+s_barrier only (no vmcnt drain): LDS h-exchange ordered; global
// gi-prefetch loads and out stores stay in flight across the barrier
// (lane-private; ordered at their use by compiler-inserted vmcnt waits).
#define TICK_BARRIER() asm volatile("s_waitcnt lgkmcnt(0)\ns_barrier" ::: "memory")

// ---------------- pass 1 (r18, verified): gi0 = X @ W0ih^T + bias, MFMA ----------------
// bias fold: cols 0..127 (R,Z) get b0ih + b0hh; cols 128..191 (N) get b0ih.
__global__ __launch_bounds__(256) void gemm_kernel(
    const float* __restrict__ x,     // [B,T,D]
    const float* __restrict__ w0ih,  // [N3,D]
    const float* __restrict__ b0ih,  // [N3]
    const float* __restrict__ b0hh,  // [N3]
    float* __restrict__ gi0,         // [B,Tc,N3]
    int* __restrict__ act,           // [T]
    int t0, int Tc) {
  __shared__ _Float16 Xs[64][72];
  __shared__ _Float16 Ws[64][72];
  __shared__ unsigned char sflag[64];

  const int tid = threadIdx.x;
  const int bid = blockIdx.x;
  const int nt = bid % 3;
  const int mt = bid / 3;
  const int tpc = Tc >> 6;
  const int b  = mt / tpc;
  const int tt = mt % tpc;
  const int c0 = nt * 64;

  const int lane = tid & 63;
  const int wid  = tid >> 6;
  const int wm = (wid >> 1) * 32;
  const int wn = (wid & 1) * 32;
  const int l15 = lane & 15;
  const int l4  = lane >> 4;

  const float* xbase = x + ((size_t)b * T_ + t0 + tt * 64) * D_;
  const float* wbase = w0ih + (size_t)c0 * D_;

  const int srow = tid >> 2;
  const int scg  = (tid & 3) << 4;
  const float* xrow = xbase + (size_t)srow * D_;
  const float* wrow = wbase + (size_t)srow * D_;

  f32x4 acc[2][2];
#pragma unroll
  for (int mi = 0; mi < 2; ++mi)
#pragma unroll
    for (int ni = 0; ni < 2; ++ni) {
      acc[mi][ni].x = 0.f; acc[mi][ni].y = 0.f;
      acc[mi][ni].z = 0.f; acc[mi][ni].w = 0.f;
    }

  bool f = false;

  for (int kt = 0; kt < D_ / 64; ++kt) {
    const int k0 = kt * 64 + scg;
    float4 xa = *(const float4*)&xrow[k0];
    float4 xb = *(const float4*)&xrow[k0 + 4];
    float4 xc = *(const float4*)&xrow[k0 + 8];
    float4 xd = *(const float4*)&xrow[k0 + 12];
    float4 wa = *(const float4*)&wrow[k0];
    float4 wb = *(const float4*)&wrow[k0 + 4];
    float4 wc = *(const float4*)&wrow[k0 + 8];
    float4 wd = *(const float4*)&wrow[k0 + 12];
    f |= (xa.x != 0.f) | (xa.y != 0.f) | (xa.z != 0.f) | (xa.w != 0.f) |
         (xb.x != 0.f) | (xb.y != 0.f) | (xb.z != 0.f) | (xb.w != 0.f) |
         (xc.x != 0.f) | (xc.y != 0.f) | (xc.z != 0.f) | (xc.w != 0.f) |
         (xd.x != 0.f) | (xd.y != 0.f) | (xd.z != 0.f) | (xd.w != 0.f);
    __syncthreads();
    {
      f16x8 p0 = {(_Float16)xa.x, (_Float16)xa.y, (_Float16)xa.z, (_Float16)xa.w,
                  (_Float16)xb.x, (_Float16)xb.y, (_Float16)xb.z, (_Float16)xb.w};
      f16x8 p1 = {(_Float16)xc.x, (_Float16)xc.y, (_Float16)xc.z, (_Float16)xc.w,
                  (_Float16)xd.x, (_Float16)xd.y, (_Float16)xd.z, (_Float16)xd.w};
      *(f16x8*)&Xs[srow][scg] = p0;
      *(f16x8*)&Xs[srow][scg + 8] = p1;
      f16x8 q0 = {(_Float16)wa.x, (_Float16)wa.y, (_Float16)wa.z, (_Float16)wa.w,
                  (_Float16)wb.x, (_Float16)wb.y, (_Float16)wb.z, (_Float16)wb.w};
      f16x8 q1 = {(_Float16)wc.x, (_Float16)wc.y, (_Float16)wc.z, (_Float16)wc.w,
                  (_Float16)wd.x, (_Float16)wd.y, (_Float16)wd.z, (_Float16)wd.w};
      *(f16x8*)&Ws[srow][scg] = q0;
      *(f16x8*)&Ws[srow][scg + 8] = q1;
    }
    __syncthreads();
#pragma unroll
    for (int ks = 0; ks < 2; ++ks) {
      const int kb = ks * 32 + l4 * 8;
      f16x8 a0 = *(const f16x8*)&Xs[wm + l15][kb];
      f16x8 a1 = *(const f16x8*)&Xs[wm + 16 + l15][kb];
      f16x8 b0 = *(const f16x8*)&Ws[wn + l15][kb];
      f16x8 b1 = *(const f16x8*)&Ws[wn + 16 + l15][kb];
      acc[0][0] = __builtin_amdgcn_mfma_f32_16x16x32_f16(a0, b0, acc[0][0], 0, 0, 0);
      acc[0][1] = __builtin_amdgcn_mfma_f32_16x16x32_f16(a0, b1, acc[0][1], 0, 0, 0);
      acc[1][0] = __builtin_amdgcn_mfma_f32_16x16x32_f16(a1, b0, acc[1][0], 0, 0, 0);
      acc[1][1] = __builtin_amdgcn_mfma_f32_16x16x32_f16(a1, b1, acc[1][1], 0, 0, 0);
    }
  }

  const int cA = c0 + wn + l15;
  const int cB = c0 + wn + 16 + l15;
  const float bias0 = b0ih[cA] + ((cA < 128) ? b0hh[cA] : 0.f);
  const float bias1 = b0ih[cB] + ((cB < 128) ? b0hh[cB] : 0.f);
  const size_t rowbase = (size_t)b * Tc + tt * 64;
#pragma unroll
  for (int mi = 0; mi < 2; ++mi)
#pragma unroll
    for (int r = 0; r < 4; ++r) {
      const int m = wm + mi * 16 + l4 * 4 + r;
      float* orow = &gi0[(rowbase + m) * N3 + c0 + wn];
      orow[l15]      = acc[mi][0][r] + bias0;
      orow[16 + l15] = acc[mi][1][r] + bias1;
    }

  if (tid < 64) sflag[tid] = 0;
  __syncthreads();
  if (f) sflag[srow] = 1;
  __syncthreads();
  if (tid < 64 && sflag[tid]) act[t0 + tt * 64 + tid] = 1;
}

// ------------- pass 2: r14's LAYER-PIPELINED scan (397us verified) + r19 edits -------------
// Edits vs r14: (1) TICK_BARRIER (no vmcnt drain) -- grp0's 12 gi-prefetch
// loads no longer drain at every barrier; (2) grp0's R/Z biases are folded
// into gi by the gemm (bsv[0]=bsv[1]=0 for grp0). Everything else identical.
__global__ __launch_bounds__(640) void scan_kernel(
    const float* __restrict__ gi0,   // [B,Tc,N3]
    const float* __restrict__ w0hh, const float* __restrict__ w1ih,
    const float* __restrict__ w1hh, const float* __restrict__ w2ih,
    const float* __restrict__ w2hh,
    const float* __restrict__ b0hh, const float* __restrict__ b1ih,
    const float* __restrict__ b1hh, const float* __restrict__ b2ih,
    const float* __restrict__ b2hh,
    const int* __restrict__ act,     // [T]
    float* __restrict__ hstate,      // [3,B,H]
    float* __restrict__ out,         // [B,T,H]
    int t0, int Tc) {
  const int b   = blockIdx.x;
  const int tid = threadIdx.x;

  __shared__ __align__(16) int4 s_w[3][192][8];       // 73728 B
  __shared__ __align__(16) _Float16 s_h[3][2][H_];    // [layer][parity][unit]
  __shared__ int s_act[T_];

  {
    const float* wsrc[3] = {w0hh, w1hh, w2hh};
    for (int i = tid; i < 3 * 192 * 8; i += 640) {
      int m = i / 1536;
      int rem = i - m * 1536;
      int row = rem >> 3;
      int c = rem & 7;
      const float* sp = wsrc[m] + (size_t)row * H_ + 8 * c;
      float4 lo = *(const float4*)sp;
      float4 hi = *(const float4*)(sp + 4);
      h2v p0 = {(_Float16)lo.x, (_Float16)lo.y};
      h2v p1 = {(_Float16)lo.z, (_Float16)lo.w};
      h2v p2 = {(_Float16)hi.x, (_Float16)hi.y};
      h2v p3 = {(_Float16)hi.z, (_Float16)hi.w};
      int4 pk;
      pk.x = __builtin_bit_cast(int, p0);
      pk.y = __builtin_bit_cast(int, p1);
      pk.z = __builtin_bit_cast(int, p2);
      pk.w = __builtin_bit_cast(int, p3);
      s_w[m][row][c ^ (row & 7)] = pk;
    }
  }
  for (int i = tid; i < Tc; i += 640) s_act[i] = act[t0 + i];

  const int grp = (tid < 128) ? 0 : (tid < 384) ? 1 : 2;
  const int lt  = tid - ((grp == 0) ? 0 : (grp == 1) ? 128 : 384);
  const int jj  = (grp == 0) ? (lt >> 1) : (lt >> 2);
  const int gg  = (grp == 0) ? (lt & 1) : (lt & 3);
  const int swz = jj & 7;

  if (tid < H_) {
    float v0 = (t0 == 0) ? 0.f : hstate[0 * B_ * H_ + b * H_ + tid];
    float v1 = (t0 == 0) ? 0.f : hstate[1 * B_ * H_ + b * H_ + tid];
    float v2 = (t0 == 0) ? 0.f : hstate[2 * B_ * H_ + b * H_ + tid];
    s_h[0][0][tid] = (_Float16)v0; s_h[0][1][tid] = (_Float16)v0;
    s_h[1][0][tid] = (_Float16)v1; s_h[1][1][tid] = (_Float16)v1;
    s_h[2][0][tid] = (_Float16)v2; s_h[2][1][tid] = (_Float16)v2;
  }
  float hreg = (t0 == 0) ? 0.f : hstate[grp * B_ * H_ + b * H_ + jj];

  int rpk[3][8];
  {
    const float* ihsrc = (grp == 2) ? w2ih : w1ih;
    const int lg = (grp == 0) ? (gg * 2) : gg;
#pragma unroll
    for (int r = 0; r < 3; ++r) {
      const float* src = ihsrc + (size_t)(jj + 64 * r) * H_ + 16 * lg;
#pragma unroll
      for (int q = 0; q < 8; ++q) {
        float2 fv = *(const float2*)(src + 2 * q);
        h2v pv = {(_Float16)fv.x, (_Float16)fv.y};
        rpk[r][q] = __builtin_bit_cast(int, pv);
      }
    }
#pragma unroll
    for (int r = 0; r < 3; ++r)
#pragma unroll
      for (int q = 0; q < 8; ++q) KEEP(rpk[r][q]);
  }

  // biases: [0]=R combined, [1]=Z combined, [2]=ih_N, [3]=hh_N
  // grp0: R/Z folded into gi by the gemm -> zero here.
  float bsv[4];
  if (grp == 0) {
    bsv[0] = 0.f; bsv[1] = 0.f; bsv[2] = 0.f;
    bsv[3] = b0hh[jj + 128];
  } else if (grp == 1) {
    bsv[0] = b1ih[jj] + b1hh[jj];
    bsv[1] = b1ih[jj + 64] + b1hh[jj + 64];
    bsv[2] = b1ih[jj + 128]; bsv[3] = b1hh[jj + 128];
  } else {
    bsv[0] = b2ih[jj] + b2hh[jj];
    bsv[1] = b2ih[jj + 64] + b2hh[jj + 64];
    bsv[2] = b2ih[jj + 128]; bsv[3] = b2hh[jj + 128];
  }

  const float* gib = gi0 + (size_t)b * Tc * N3;
  float giR = 0.f, giZ = 0.f, giN = 0.f;
  if (grp == 0) { giR = gib[jj]; giZ = gib[jj + 64]; giN = gib[jj + 128]; }

  __syncthreads();   // initial full barrier

  for (int i = 0; i < Tc + 2; ++i) {
    const int p = i & 1;
    if (grp == 0) {
      if (i < Tc) {
        const int4* hp = (const int4*)s_h[0][p ^ 1];
        int4 h0s = hp[4 * gg + 0], h1s = hp[4 * gg + 1];
        int4 h2s = hp[4 * gg + 2], h3s = hp[4 * gg + 3];
        float R0 = 0, R1 = 0, Z0 = 0, Z1 = 0, N0 = 0, N1 = 0;
#pragma unroll
        for (int k = 0; k < 4; ++k) {
          int pc = (4 * gg + k) ^ swz;
          int4 hk = (k == 0) ? h0s : (k == 1) ? h1s : (k == 2) ? h2s : h3s;
          dot4acc(s_w[0][jj][pc],       hk, R0, R1);
          dot4acc(s_w[0][jj + 64][pc],  hk, Z0, Z1);
          dot4acc(s_w[0][jj + 128][pc], hk, N0, N1);
        }
        float dR = red2(R0 + R1);
        float dZ = red2(Z0 + Z1);
        float dN = red2(N0 + N1) + bsv[3];
        bool a = (s_act[i] != 0);
        float r = sigm_f(giR + dR);
        float z = sigm_f(giZ + dZ);
        float n = tanh_f(giN + r * dN);
        float hn = (1.0f - z) * n + z * hreg;
        hreg = a ? hn : hreg;
        if (gg == 0) s_h[0][p][jj] = (_Float16)hreg;
        int tn = (i + 1 < Tc) ? i + 1 : i;   // prefetch across barrier
        giR = gib[(size_t)tn * N3 + jj];
        giZ = gib[(size_t)tn * N3 + jj + 64];
        giN = gib[(size_t)tn * N3 + jj + 128];
      }
    } else if (grp == 1) {
      if (i >= 1 && i <= Tc) {
        const int4* h0p = (const int4*)s_h[0][p ^ 1];
        const int4* h1p = (const int4*)s_h[1][p ^ 1];
        int4 x0 = h0p[2 * gg], x1 = h0p[2 * gg + 1];
        int4 y0 = h1p[2 * gg], y1 = h1p[2 * gg + 1];
        float vR0 = 0, vR1 = 0, vZ0 = 0, vZ1 = 0;
        float iN0 = 0, iN1 = 0, hN0 = 0, hN1 = 0;
        dot8reg(rpk[0], x0, x1, vR0, vR1);
        dot8reg(rpk[1], x0, x1, vZ0, vZ1);
        dot8reg(rpk[2], x0, x1, iN0, iN1);
        int pc0 = (2 * gg) ^ swz, pc1 = (2 * gg + 1) ^ swz;
        dot4acc(s_w[1][jj][pc0],       y0, vR0, vR1);
        dot4acc(s_w[1][jj][pc1],       y1, vR0, vR1);
        dot4acc(s_w[1][jj + 64][pc0],  y0, vZ0, vZ1);
        dot4acc(s_w[1][jj + 64][pc1],  y1, vZ0, vZ1);
        dot4acc(s_w[1][jj + 128][pc0], y0, hN0, hN1);
        dot4acc(s_w[1][jj + 128][pc1], y1, hN0, hN1);
        float sR = red4(vR0 + vR1) + bsv[0];
        float sZ = red4(vZ0 + vZ1) + bsv[1];
        float iN = red4(iN0 + iN1) + bsv[2];
        float hN = red4(hN0 + hN1) + bsv[3];
        bool a = (s_act[i - 1] != 0);
        float r = sigm_f(sR);
        float z = sigm_f(sZ);
        float n = tanh_f(iN + r * hN);
        float hn = (1.0f - z) * n + z * hreg;
        hreg = a ? hn : hreg;
        if (gg == 0) s_h[1][p][jj] = (_Float16)hreg;
      }
    } else {
      if (i >= 2) {
        const int4* h1p = (const int4*)s_h[1][p ^ 1];
        const int4* h2p = (const int4*)s_h[2][p ^ 1];
        int4 x0 = h1p[2 * gg], x1 = h1p[2 * gg + 1];
        int4 y0 = h2p[2 * gg], y1 = h2p[2 * gg + 1];
        float vR0 = 0, vR1 = 0, vZ0 = 0, vZ1 = 0;
        float iN0 = 0, iN1 = 0, hN0 = 0, hN1 = 0;
        dot8reg(rpk[0], x0, x1, vR0, vR1);
        dot8reg(rpk[1], x0, x1, vZ0, vZ1);
        dot8reg(rpk[2], x0, x1, iN0, iN1);
        int pc0 = (2 * gg) ^ swz, pc1 = (2 * gg + 1) ^ swz;
        dot4acc(s_w[2][jj][pc0],       y0, vR0, vR1);
        dot4acc(s_w[2][jj][pc1],       y1, vR0, vR1);
        dot4acc(s_w[2][jj + 64][pc0],  y0, vZ0, vZ1);
        dot4acc(s_w[2][jj + 64][pc1],  y1, vZ0, vZ1);
        dot4acc(s_w[2][jj + 128][pc0], y0, hN0, hN1);
        dot4acc(s_w[2][jj + 128][pc1], y1, hN0, hN1);
        float sR = red4(vR0 + vR1) + bsv[0];
        float sZ = red4(vZ0 + vZ1) + bsv[1];
        float iN = red4(iN0 + iN1) + bsv[2];
        float hN = red4(hN0 + hN1) + bsv[3];
        bool a = (s_act[i - 2] != 0);
        float r = sigm_f(sR);
        float z = sigm_f(sZ);
        float n = tanh_f(iN + r * hN);
        float hn = (1.0f - z) * n + z * hreg;
        hreg = a ? hn : hreg;
        if (gg == 0) {
          s_h[2][p][jj] = (_Float16)hreg;
          out[((size_t)b * T_ + t0 + (i - 2)) * H_ + jj] = a ? hreg : 0.0f;
        }
      }
    }
    TICK_BARRIER();   // lgkmcnt(0)+s_barrier only: no per-tick vmcnt drain
  }

  if (gg == 0) hstate[grp * B_ * H_ + b * H_ + jj] = hreg;
}

extern "C" void kernel_launch(void* const* d_in, const int* in_sizes, int n_in,
                              void* d_out, int out_size, void* d_ws, size_t ws_size,
                              hipStream_t stream) {
  const float* x    = (const float*)d_in[0];
  const float* w0ih = (const float*)d_in[1];
  const float* w0hh = (const float*)d_in[2];
  const float* b0ih = (const float*)d_in[3];
  const float* b0hh = (const float*)d_in[4];
  const float* w1ih = (const float*)d_in[5];
  const float* w1hh = (const float*)d_in[6];
  const float* b1ih = (const float*)d_in[7];
  const float* b1hh = (const float*)d_in[8];
  const float* w2ih = (const float*)d_in[9];
  const float* w2hh = (const float*)d_in[10];
  const float* b2ih = (const float*)d_in[11];
  const float* b2hh = (const float*)d_in[12];
  float* out = (float*)d_out;

  char* p = (char*)d_ws;
  int* act      = (int*)p;    p += 4096;
  float* hstate = (float*)p;  p += (size_t)3 * B_ * H_ * 4;
  size_t fixed = (size_t)(p - (char*)d_ws);

  int Tc = T_;
  while (Tc > 64 && fixed + (size_t)B_ * Tc * N3 * 4 > ws_size) Tc >>= 1;
  float* gi0 = (float*)p;

  hipMemsetAsync(act, 0, T_ * sizeof(int), stream);
  for (int t0 = 0; t0 < T_; t0 += Tc) {
    gemm_kernel<<<dim3(B_ * (Tc / 64) * 3), 256, 0, stream>>>(
        x, w0ih, b0ih, b0hh, gi0, act, t0, Tc);
    scan_kernel<<<B_, 640, 0, stream>>>(
        gi0, w0hh, w1ih, w1hh, w2ih, w2hh,
        b0hh, b1ih, b1hh, b2ih, b2hh, act, hstate, out, t0, Tc);
  }
}

// Round 20
// 427.821 us; speedup vs baseline: 1.3939x; 1.0423x over previous
//
#include <hip/hip_runtime.h>

#define B_ 128
#define T_ 512
#define D_ 512
#define H_ 64
#define N3 192   // 3*H

#if __has_builtin(__builtin_amdgcn_rcpf)
#define RCP(x) __builtin_amdgcn_rcpf(x)
#else
#define RCP(x) (1.0f / (x))
#endif

typedef _Float16 h2v __attribute__((ext_vector_type(2)));
typedef _Float16 f16x8 __attribute__((ext_vector_type(8)));
typedef float f32x4 __attribute__((ext_vector_type(4)));

__device__ __forceinline__ float sigm_f(float x) {
  return RCP(1.0f + __expf(-x));
}
__device__ __forceinline__ float tanh_f(float x) {
  float e = __expf(-2.0f * fabsf(x));
  float t = (1.0f - e) * RCP(1.0f + e);
  return copysignf(t, x);
}

// DPP lane-group sums (bound_ctrl=1).
template <int CTRL>
__device__ __forceinline__ float dpp_add(float v) {
  int t = __builtin_amdgcn_update_dpp(0, __float_as_int(v), CTRL, 0xF, 0xF, true);
  return v + __int_as_float(t);
}
__device__ __forceinline__ float red2(float v) { return dpp_add<0xB1>(v); }
__device__ __forceinline__ float red4(float v) {
  v = dpp_add<0xB1>(v);
  v = dpp_add<0x4E>(v);
  return v;
}

__device__ __forceinline__ void dot8reg(const int* w, int4 a, int4 b,
                                        float& s0, float& s1) {
  s0 = __builtin_amdgcn_fdot2(__builtin_bit_cast(h2v, w[0]),
                              __builtin_bit_cast(h2v, a.x), s0, false);
  s1 = __builtin_amdgcn_fdot2(__builtin_bit_cast(h2v, w[1]),
                              __builtin_bit_cast(h2v, a.y), s1, false);
  s0 = __builtin_amdgcn_fdot2(__builtin_bit_cast(h2v, w[2]),
                              __builtin_bit_cast(h2v, a.z), s0, false);
  s1 = __builtin_amdgcn_fdot2(__builtin_bit_cast(h2v, w[3]),
                              __builtin_bit_cast(h2v, a.w), s1, false);
  s0 = __builtin_amdgcn_fdot2(__builtin_bit_cast(h2v, w[4]),
                              __builtin_bit_cast(h2v, b.x), s0, false);
  s1 = __builtin_amdgcn_fdot2(__builtin_bit_cast(h2v, w[5]),
                              __builtin_bit_cast(h2v, b.y), s1, false);
  s0 = __builtin_amdgcn_fdot2(__builtin_bit_cast(h2v, w[6]),
                              __builtin_bit_cast(h2v, b.z), s0, false);
  s1 = __builtin_amdgcn_fdot2(__builtin_bit_cast(h2v, w[7]),
                              __builtin_bit_cast(h2v, b.w), s1, false);
}
__device__ __forceinline__ void dot16reg(const int* w, int4 a, int4 b,
                                         int4 c, int4 d, float& s0, float& s1) {
  dot8reg(w, a, b, s0, s1);
  dot8reg(w + 8, c, d, s0, s1);
}

#define KEEP(x) asm volatile("" : "+v"(x))

// lgkmcnt(0)+s_barrier only (no vmcnt drain).
#define TICK_BARRIER() asm volatile("s_waitcnt lgkmcnt(0)\ns_barrier" ::: "memory")

// ---------------- pass 1 (r18, verified): gi0 = X @ W0ih^T + bias, MFMA ----------------
__global__ __launch_bounds__(256) void gemm_kernel(
    const float* __restrict__ x,     // [B,T,D]
    const float* __restrict__ w0ih,  // [N3,D]
    const float* __restrict__ b0ih,  // [N3]
    const float* __restrict__ b0hh,  // [N3]
    float* __restrict__ gi0,         // [B,Tc,N3]
    int* __restrict__ act,           // [T]
    int t0, int Tc) {
  __shared__ _Float16 Xs[64][72];
  __shared__ _Float16 Ws[64][72];
  __shared__ unsigned char sflag[64];

  const int tid = threadIdx.x;
  const int bid = blockIdx.x;
  const int nt = bid % 3;
  const int mt = bid / 3;
  const int tpc = Tc >> 6;
  const int b  = mt / tpc;
  const int tt = mt % tpc;
  const int c0 = nt * 64;

  const int lane = tid & 63;
  const int wid  = tid >> 6;
  const int wm = (wid >> 1) * 32;
  const int wn = (wid & 1) * 32;
  const int l15 = lane & 15;
  const int l4  = lane >> 4;

  const float* xbase = x + ((size_t)b * T_ + t0 + tt * 64) * D_;
  const float* wbase = w0ih + (size_t)c0 * D_;

  const int srow = tid >> 2;
  const int scg  = (tid & 3) << 4;
  const float* xrow = xbase + (size_t)srow * D_;
  const float* wrow = wbase + (size_t)srow * D_;

  f32x4 acc[2][2];
#pragma unroll
  for (int mi = 0; mi < 2; ++mi)
#pragma unroll
    for (int ni = 0; ni < 2; ++ni) {
      acc[mi][ni].x = 0.f; acc[mi][ni].y = 0.f;
      acc[mi][ni].z = 0.f; acc[mi][ni].w = 0.f;
    }

  bool f = false;

  for (int kt = 0; kt < D_ / 64; ++kt) {
    const int k0 = kt * 64 + scg;
    float4 xa = *(const float4*)&xrow[k0];
    float4 xb = *(const float4*)&xrow[k0 + 4];
    float4 xc = *(const float4*)&xrow[k0 + 8];
    float4 xd = *(const float4*)&xrow[k0 + 12];
    float4 wa = *(const float4*)&wrow[k0];
    float4 wb = *(const float4*)&wrow[k0 + 4];
    float4 wc = *(const float4*)&wrow[k0 + 8];
    float4 wd = *(const float4*)&wrow[k0 + 12];
    f |= (xa.x != 0.f) | (xa.y != 0.f) | (xa.z != 0.f) | (xa.w != 0.f) |
         (xb.x != 0.f) | (xb.y != 0.f) | (xb.z != 0.f) | (xb.w != 0.f) |
         (xc.x != 0.f) | (xc.y != 0.f) | (xc.z != 0.f) | (xc.w != 0.f) |
         (xd.x != 0.f) | (xd.y != 0.f) | (xd.z != 0.f) | (xd.w != 0.f);
    __syncthreads();
    {
      f16x8 p0 = {(_Float16)xa.x, (_Float16)xa.y, (_Float16)xa.z, (_Float16)xa.w,
                  (_Float16)xb.x, (_Float16)xb.y, (_Float16)xb.z, (_Float16)xb.w};
      f16x8 p1 = {(_Float16)xc.x, (_Float16)xc.y, (_Float16)xc.z, (_Float16)xc.w,
                  (_Float16)xd.x, (_Float16)xd.y, (_Float16)xd.z, (_Float16)xd.w};
      *(f16x8*)&Xs[srow][scg] = p0;
      *(f16x8*)&Xs[srow][scg + 8] = p1;
      f16x8 q0 = {(_Float16)wa.x, (_Float16)wa.y, (_Float16)wa.z, (_Float16)wa.w,
                  (_Float16)wb.x, (_Float16)wb.y, (_Float16)wb.z, (_Float16)wb.w};
      f16x8 q1 = {(_Float16)wc.x, (_Float16)wc.y, (_Float16)wc.z, (_Float16)wc.w,
                  (_Float16)wd.x, (_Float16)wd.y, (_Float16)wd.z, (_Float16)wd.w};
      *(f16x8*)&Ws[srow][scg] = q0;
      *(f16x8*)&Ws[srow][scg + 8] = q1;
    }
    __syncthreads();
#pragma unroll
    for (int ks = 0; ks < 2; ++ks) {
      const int kb = ks * 32 + l4 * 8;
      f16x8 a0 = *(const f16x8*)&Xs[wm + l15][kb];
      f16x8 a1 = *(const f16x8*)&Xs[wm + 16 + l15][kb];
      f16x8 b0 = *(const f16x8*)&Ws[wn + l15][kb];
      f16x8 b1 = *(const f16x8*)&Ws[wn + 16 + l15][kb];
      acc[0][0] = __builtin_amdgcn_mfma_f32_16x16x32_f16(a0, b0, acc[0][0], 0, 0, 0);
      acc[0][1] = __builtin_amdgcn_mfma_f32_16x16x32_f16(a0, b1, acc[0][1], 0, 0, 0);
      acc[1][0] = __builtin_amdgcn_mfma_f32_16x16x32_f16(a1, b0, acc[1][0], 0, 0, 0);
      acc[1][1] = __builtin_amdgcn_mfma_f32_16x16x32_f16(a1, b1, acc[1][1], 0, 0, 0);
    }
  }

  const int cA = c0 + wn + l15;
  const int cB = c0 + wn + 16 + l15;
  const float bias0 = b0ih[cA] + ((cA < 128) ? b0hh[cA] : 0.f);
  const float bias1 = b0ih[cB] + ((cB < 128) ? b0hh[cB] : 0.f);
  const size_t rowbase = (size_t)b * Tc + tt * 64;
#pragma unroll
  for (int mi = 0; mi < 2; ++mi)
#pragma unroll
    for (int r = 0; r < 4; ++r) {
      const int m = wm + mi * 16 + l4 * 4 + r;
      float* orow = &gi0[(rowbase + m) * N3 + c0 + wn];
      orow[l15]      = acc[mi][0][r] + bias0;
      orow[16 + l15] = acc[mi][1][r] + bias1;
    }

  if (tid < 64) sflag[tid] = 0;
  __syncthreads();
  if (f) sflag[srow] = 1;
  __syncthreads();
  if (tid < 64 && sflag[tid]) act[t0 + tt * 64 + tid] = 1;
}

// ------------- pass 2: r19 layer-pipelined scan, hh-weights REGISTERIZED -------------
// r19 tick had ~600 cyc/tick of DS sweeps re-reading all 3 hh matrices from
// LDS. Now ALL weights live in registers: grp0 holds 48 dwords (3 rows x
// 32-wide f16x2), grp1/2 hold 24 ih + 24 hh dwords. The 80KB dummy LDS pad
// (volatile-touched) caps occupancy at 1 WG/CU -> ~3 waves/SIMD -> ~168-VGPR
// allocator budget, so the ~85-reg demand fits WITHOUT the spills that killed
// rounds 2-11 (those ran at 64-128-reg budgets). DS per tick -> h-exchange
// only (~128B). Schedule/sync/math identical to r19.
__global__ __launch_bounds__(640) void scan_kernel(
    const float* __restrict__ gi0,   // [B,Tc,N3]
    const float* __restrict__ w0hh, const float* __restrict__ w1ih,
    const float* __restrict__ w1hh, const float* __restrict__ w2ih,
    const float* __restrict__ w2hh,
    const float* __restrict__ b0hh, const float* __restrict__ b1ih,
    const float* __restrict__ b1hh, const float* __restrict__ b2ih,
    const float* __restrict__ b2hh,
    const int* __restrict__ act,     // [T]
    float* __restrict__ hstate,      // [3,B,H]
    float* __restrict__ out,         // [B,T,H]
    int t0, int Tc) {
  const int b   = blockIdx.x;
  const int tid = threadIdx.x;

  __shared__ __align__(16) char s_pad[81920];         // occupancy cap: 1 WG/CU
  __shared__ __align__(16) _Float16 s_h[3][2][H_];    // [layer][parity][unit]
  __shared__ int s_act[T_];

  if (tid == 0) { volatile char* vp = s_pad; vp[0] = 0; }  // keep pad alive

  for (int i = tid; i < Tc; i += 640) s_act[i] = act[t0 + i];

  const int grp = (tid < 128) ? 0 : (tid < 384) ? 1 : 2;
  const int lt  = tid - ((grp == 0) ? 0 : (grp == 1) ? 128 : 384);
  const int jj  = (grp == 0) ? (lt >> 1) : (lt >> 2);
  const int gg  = (grp == 0) ? (lt & 1) : (lt & 3);

  if (tid < H_) {
    float v0 = (t0 == 0) ? 0.f : hstate[0 * B_ * H_ + b * H_ + tid];
    float v1 = (t0 == 0) ? 0.f : hstate[1 * B_ * H_ + b * H_ + tid];
    float v2 = (t0 == 0) ? 0.f : hstate[2 * B_ * H_ + b * H_ + tid];
    s_h[0][0][tid] = (_Float16)v0; s_h[0][1][tid] = (_Float16)v0;
    s_h[1][0][tid] = (_Float16)v1; s_h[1][1][tid] = (_Float16)v1;
    s_h[2][0][tid] = (_Float16)v2; s_h[2][1][tid] = (_Float16)v2;
  }
  float hreg = (t0 == 0) ? 0.f : hstate[grp * B_ * H_ + b * H_ + jj];

  // ---- register weights ----
  int rw0[3][16];   // grp0: W0hh rows {jj,jj+64,jj+128}, cols [32gg,32gg+32)
  int rpk[3][8];    // grp1/2: Wih rows, cols [16gg,16gg+16)
  int rhh[3][8];    // grp1/2: Whh rows, cols [16gg,16gg+16)
  if (grp == 0) {
#pragma unroll
    for (int r = 0; r < 3; ++r) {
      const float* src = w0hh + (size_t)(jj + 64 * r) * H_ + 32 * gg;
#pragma unroll
      for (int q = 0; q < 16; ++q) {
        float2 fv = *(const float2*)(src + 2 * q);
        h2v pv = {(_Float16)fv.x, (_Float16)fv.y};
        rw0[r][q] = __builtin_bit_cast(int, pv);
      }
    }
#pragma unroll
    for (int r = 0; r < 3; ++r)
#pragma unroll
      for (int q = 0; q < 16; ++q) KEEP(rw0[r][q]);
  } else {
    const float* ihsrc = (grp == 2) ? w2ih : w1ih;
    const float* hhsrc = (grp == 2) ? w2hh : w1hh;
#pragma unroll
    for (int r = 0; r < 3; ++r) {
      const float* si = ihsrc + (size_t)(jj + 64 * r) * H_ + 16 * gg;
      const float* sh = hhsrc + (size_t)(jj + 64 * r) * H_ + 16 * gg;
#pragma unroll
      for (int q = 0; q < 8; ++q) {
        float2 fi = *(const float2*)(si + 2 * q);
        float2 fh = *(const float2*)(sh + 2 * q);
        h2v pi = {(_Float16)fi.x, (_Float16)fi.y};
        h2v ph = {(_Float16)fh.x, (_Float16)fh.y};
        rpk[r][q] = __builtin_bit_cast(int, pi);
        rhh[r][q] = __builtin_bit_cast(int, ph);
      }
    }
#pragma unroll
    for (int r = 0; r < 3; ++r)
#pragma unroll
      for (int q = 0; q < 8; ++q) { KEEP(rpk[r][q]); KEEP(rhh[r][q]); }
  }

  // biases: [0]=R combined, [1]=Z combined, [2]=ih_N, [3]=hh_N
  float bsv[4];
  if (grp == 0) {
    bsv[0] = 0.f; bsv[1] = 0.f; bsv[2] = 0.f;
    bsv[3] = b0hh[jj + 128];
  } else if (grp == 1) {
    bsv[0] = b1ih[jj] + b1hh[jj];
    bsv[1] = b1ih[jj + 64] + b1hh[jj + 64];
    bsv[2] = b1ih[jj + 128]; bsv[3] = b1hh[jj + 128];
  } else {
    bsv[0] = b2ih[jj] + b2hh[jj];
    bsv[1] = b2ih[jj + 64] + b2hh[jj + 64];
    bsv[2] = b2ih[jj + 128]; bsv[3] = b2hh[jj + 128];
  }

  const float* gib = gi0 + (size_t)b * Tc * N3;
  float giR = 0.f, giZ = 0.f, giN = 0.f;
  if (grp == 0) { giR = gib[jj]; giZ = gib[jj + 64]; giN = gib[jj + 128]; }

  __syncthreads();   // initial full barrier

  for (int i = 0; i < Tc + 2; ++i) {
    const int p = i & 1;
    if (grp == 0) {
      if (i < Tc) {
        const int4* hp = (const int4*)s_h[0][p ^ 1];
        int4 h0s = hp[4 * gg + 0], h1s = hp[4 * gg + 1];
        int4 h2s = hp[4 * gg + 2], h3s = hp[4 * gg + 3];
        float R0 = 0, R1 = 0, Z0 = 0, Z1 = 0, N0 = 0, N1 = 0;
        dot16reg(rw0[0], h0s, h1s, h2s, h3s, R0, R1);
        dot16reg(rw0[1], h0s, h1s, h2s, h3s, Z0, Z1);
        dot16reg(rw0[2], h0s, h1s, h2s, h3s, N0, N1);
        float dR = red2(R0 + R1);
        float dZ = red2(Z0 + Z1);
        float dN = red2(N0 + N1) + bsv[3];
        bool a = (s_act[i] != 0);
        float r = sigm_f(giR + dR);
        float z = sigm_f(giZ + dZ);
        float n = tanh_f(giN + r * dN);
        float hn = (1.0f - z) * n + z * hreg;
        hreg = a ? hn : hreg;
        if (gg == 0) s_h[0][p][jj] = (_Float16)hreg;
        int tn = (i + 1 < Tc) ? i + 1 : i;   // prefetch across barrier
        giR = gib[(size_t)tn * N3 + jj];
        giZ = gib[(size_t)tn * N3 + jj + 64];
        giN = gib[(size_t)tn * N3 + jj + 128];
      }
    } else if (grp == 1) {
      if (i >= 1 && i <= Tc) {
        const int4* h0p = (const int4*)s_h[0][p ^ 1];
        const int4* h1p = (const int4*)s_h[1][p ^ 1];
        int4 x0 = h0p[2 * gg], x1 = h0p[2 * gg + 1];
        int4 y0 = h1p[2 * gg], y1 = h1p[2 * gg + 1];
        float vR0 = 0, vR1 = 0, vZ0 = 0, vZ1 = 0;
        float iN0 = 0, iN1 = 0, hN0 = 0, hN1 = 0;
        dot8reg(rpk[0], x0, x1, vR0, vR1);
        dot8reg(rhh[0], y0, y1, vR0, vR1);
        dot8reg(rpk[1], x0, x1, vZ0, vZ1);
        dot8reg(rhh[1], y0, y1, vZ0, vZ1);
        dot8reg(rpk[2], x0, x1, iN0, iN1);
        dot8reg(rhh[2], y0, y1, hN0, hN1);
        float sR = red4(vR0 + vR1) + bsv[0];
        float sZ = red4(vZ0 + vZ1) + bsv[1];
        float iN = red4(iN0 + iN1) + bsv[2];
        float hN = red4(hN0 + hN1) + bsv[3];
        bool a = (s_act[i - 1] != 0);
        float r = sigm_f(sR);
        float z = sigm_f(sZ);
        float n = tanh_f(iN + r * hN);
        float hn = (1.0f - z) * n + z * hreg;
        hreg = a ? hn : hreg;
        if (gg == 0) s_h[1][p][jj] = (_Float16)hreg;
      }
    } else {
      if (i >= 2) {
        const int4* h1p = (const int4*)s_h[1][p ^ 1];
        const int4* h2p = (const int4*)s_h[2][p ^ 1];
        int4 x0 = h1p[2 * gg], x1 = h1p[2 * gg + 1];
        int4 y0 = h2p[2 * gg], y1 = h2p[2 * gg + 1];
        float vR0 = 0, vR1 = 0, vZ0 = 0, vZ1 = 0;
        float iN0 = 0, iN1 = 0, hN0 = 0, hN1 = 0;
        dot8reg(rpk[0], x0, x1, vR0, vR1);
        dot8reg(rhh[0], y0, y1, vR0, vR1);
        dot8reg(rpk[1], x0, x1, vZ0, vZ1);
        dot8reg(rhh[1], y0, y1, vZ0, vZ1);
        dot8reg(rpk[2], x0, x1, iN0, iN1);
        dot8reg(rhh[2], y0, y1, hN0, hN1);
        float sR = red4(vR0 + vR1) + bsv[0];
        float sZ = red4(vZ0 + vZ1) + bsv[1];
        float iN = red4(iN0 + iN1) + bsv[2];
        float hN = red4(hN0 + hN1) + bsv[3];
        bool a = (s_act[i - 2] != 0);
        float r = sigm_f(sR);
        float z = sigm_f(sZ);
        float n = tanh_f(iN + r * hN);
        float hn = (1.0f - z) * n + z * hreg;
        hreg = a ? hn : hreg;
        if (gg == 0) {
          s_h[2][p][jj] = (_Float16)hreg;
          out[((size_t)b * T_ + t0 + (i - 2)) * H_ + jj] = a ? hreg : 0.0f;
        }
      }
    }
    TICK_BARRIER();   // lgkmcnt(0)+s_barrier only
  }

  if (gg == 0) hstate[grp * B_ * H_ + b * H_ + jj] = hreg;
}

extern "C" void kernel_launch(void* const* d_in, const int* in_sizes, int n_in,
                              void* d_out, int out_size, void* d_ws, size_t ws_size,
                              hipStream_t stream) {
  const float* x    = (const float*)d_in[0];
  const float* w0ih = (const float*)d_in[1];
  const float* w0hh = (const float*)d_in[2];
  const float* b0ih = (const float*)d_in[3];
  const float* b0hh = (const float*)d_in[4];
  const float* w1ih = (const float*)d_in[5];
  const float* w1hh = (const float*)d_in[6];
  const float* b1ih = (const float*)d_in[7];
  const float* b1hh = (const float*)d_in[8];
  const float* w2ih = (const float*)d_in[9];
  const float* w2hh = (const float*)d_in[10];
  const float* b2ih = (const float*)d_in[11];
  const float* b2hh = (const float*)d_in[12];
  float* out = (float*)d_out;

  char* p = (char*)d_ws;
  int* act      = (int*)p;    p += 4096;
  float* hstate = (float*)p;  p += (size_t)3 * B_ * H_ * 4;
  size_t fixed = (size_t)(p - (char*)d_ws);

  int Tc = T_;
  while (Tc > 64 && fixed + (size_t)B_ * Tc * N3 * 4 > ws_size) Tc >>= 1;
  float* gi0 = (float*)p;

  hipMemsetAsync(act, 0, T_ * sizeof(int), stream);
  for (int t0 = 0; t0 < T_; t0 += Tc) {
    gemm_kernel<<<dim3(B_ * (Tc / 64) * 3), 256, 0, stream>>>(
        x, w0ih, b0ih, b0hh, gi0, act, t0, Tc);
    scan_kernel<<<B_, 640, 0, stream>>>(
        gi0, w0hh, w1ih, w1hh, w2ih, w2hh,
        b0hh, b1ih, b1hh, b2ih, b2hh, act, hstate, out, t0, Tc);
  }
}